// Round 4
// baseline (260.641 us; speedup 1.0000x reference)
//
#include <hip/hip_runtime.h>
#include <math.h>

#define NB 2
#define NC 256
#define NS 4096
#define NG 32
#define CPG 8
#define NH 4
#define DK 64
#define NQKV 768
#define QS 0.18033688011112042f   /* 0.125 * log2(e): folds attn scale + exp->exp2 */

typedef __attribute__((ext_vector_type(8))) short short8;
typedef __attribute__((ext_vector_type(4))) float f32x4;
typedef __attribute__((ext_vector_type(2))) unsigned int uint2v;

__device__ __forceinline__ short f2bf(float f){
  union { float f; unsigned u; } v; v.f = f;
  unsigned r = v.u + 0x7fffu + ((v.u >> 16) & 1u);
  return (short)(r >> 16);
}
__device__ __forceinline__ float ex2(float x){          // hardware 2^x
  float y; asm("v_exp_f32 %0, %1" : "=v"(y) : "v"(x)); return y;
}
__device__ __forceinline__ unsigned cvtpk(float lo, float hi){ // bf16(lo)|bf16(hi)<<16, RNE
  unsigned u; asm("v_cvt_pk_bf16_f32 %0, %1, %2" : "=v"(u) : "v"(lo), "v"(hi)); return u;
}

// ---- K1: group-norm stats ----
__global__ __launch_bounds__(256) void k_gnstats(const float* __restrict__ x,
                                                 float* __restrict__ mean,
                                                 float* __restrict__ rstd){
  int bg = blockIdx.x;
  const float* base = x + (size_t)bg * (CPG*NS);
  float s = 0.f, ss = 0.f;
  for (int i = threadIdx.x; i < CPG*NS; i += 256){
    float v = base[i]; s += v; ss += v*v;
  }
  for (int o = 32; o > 0; o >>= 1){ s += __shfl_down(s, o); ss += __shfl_down(ss, o); }
  __shared__ float red[8];
  int w = threadIdx.x >> 6;
  if ((threadIdx.x & 63) == 0){ red[w] = s; red[4+w] = ss; }
  __syncthreads();
  if (threadIdx.x == 0){
    float S  = red[0]+red[1]+red[2]+red[3];
    float SS = red[4]+red[5]+red[6]+red[7];
    const float inv = 1.f/(float)(CPG*NS);
    float m = S*inv; float var = SS*inv - m*m;
    mean[bg] = m; rstd[bg] = rsqrtf(var + 1e-5f);
  }
}

// ---- K2: normalize + transpose [B,C,S] -> h[B,S,C] bf16 ----
__global__ __launch_bounds__(256) void k_gnapply(const float* __restrict__ x,
                                                 const float* __restrict__ gw,
                                                 const float* __restrict__ gb,
                                                 const float* __restrict__ mean,
                                                 const float* __restrict__ rstd,
                                                 short* __restrict__ h){
  __shared__ short tile[64][258];
  int b  = blockIdx.x >> 6;
  int s0 = (blockIdx.x & 63) << 6;
  int sl = threadIdx.x & 63;
  int c0 = threadIdx.x >> 6;
  for (int ci = 0; ci < NC; ci += 4){
    int c = ci + c0;
    int sg = (b << 5) + (c >> 3);
    float v  = x[((size_t)b*NC + c)*NS + s0 + sl];
    float hn = (v - mean[sg]) * rstd[sg] * gw[c] + gb[c];
    tile[sl][c] = f2bf(hn);
  }
  __syncthreads();
  for (int it = 0; it < 32; ++it){
    int idx = it*256 + threadIdx.x;
    int row = idx >> 7, col = (idx & 127) << 1;
    unsigned p = ((unsigned)(unsigned short)tile[row][col]) |
                 (((unsigned)(unsigned short)tile[row][col+1]) << 16);
    *(unsigned*)&h[((size_t)b*NS + s0 + row)*NC + col] = p;
  }
}

// ---- K3: weights f32 -> bf16 ----
__global__ __launch_bounds__(256) void k_cvtw(const float* __restrict__ pw,
                                              const float* __restrict__ ow,
                                              short* __restrict__ pwb,
                                              short* __restrict__ owb){
  int i = blockIdx.x*256 + threadIdx.x;
  if (i < NQKV*NC) pwb[i] = f2bf(pw[i]);
  if (i < NC*NC)   owb[i] = f2bf(ow[i]);
}

// ---- K4: QKV GEMM with scatter epilogue; q gets QS scale folded in ----
__global__ __launch_bounds__(256) void k_qkv(const short* __restrict__ h,
                                             const short* __restrict__ wb,
                                             const float* __restrict__ pb,
                                             short* __restrict__ qo,
                                             short* __restrict__ ko,
                                             short* __restrict__ vto){
  __shared__ short As[128][40];
  __shared__ short Bs[128][40];
  int m0 = blockIdx.x << 7;
  int n0 = blockIdx.y << 7;
  int tid = threadIdx.x;
  int lane = tid & 63, wid = tid >> 6;
  int wm = (wid >> 1) << 6, wn = (wid & 1) << 6;
  int l15 = lane & 15, lg = lane >> 4;
  const f32x4 fz = {0.f,0.f,0.f,0.f};
  f32x4 acc[4][4];
  for (int i=0;i<4;i++) for(int j=0;j<4;j++) acc[i][j] = fz;
  for (int k0 = 0; k0 < NC; k0 += 32){
    __syncthreads();
    for (int it = 0; it < 2; ++it){
      int c = it*256 + tid;
      int r = c >> 2, kk8 = (c & 3) << 3;
      *(short8*)&As[r][kk8] = *(const short8*)&h [((size_t)(m0 + r))*NC + k0 + kk8];
      *(short8*)&Bs[r][kk8] = *(const short8*)&wb[((size_t)(n0 + r))*NC + k0 + kk8];
    }
    __syncthreads();
    short8 a[4], b[4];
    for (int mf=0; mf<4; ++mf) a[mf] = *(const short8*)&As[wm + mf*16 + l15][lg*8];
    for (int nf=0; nf<4; ++nf) b[nf] = *(const short8*)&Bs[wn + nf*16 + l15][lg*8];
    for (int mf=0; mf<4; ++mf)
      for (int nf=0; nf<4; ++nf)
        acc[mf][nf] = __builtin_amdgcn_mfma_f32_16x16x32_bf16(a[mf], b[nf], acc[mf][nf], 0,0,0);
  }
  for (int mf=0; mf<4; ++mf)
    for (int nf=0; nf<4; ++nf)
      for (int r=0; r<4; ++r){
        int m = m0 + wm + mf*16 + lg*4 + r;
        int o = n0 + wn + nf*16 + l15;
        float val = acc[mf][nf][r] + pb[o];
        int b_ = m >> 12, s = m & 4095;
        int hh = o / 192, rem = o - hh*192;
        int t = rem >> 6, d = rem & 63;
        size_t bh = (size_t)(b_*NH + hh);
        if (t == 0)      qo [(bh*NS + s)*DK + d] = f2bf(val * QS);
        else if (t == 1) ko [(bh*NS + s)*DK + d] = f2bf(val);
        else             vto[(bh*DK + d)*NS + s] = f2bf(val);
      }
}

// ---- K5: flash attention, 8 waves: waves 0-3 kv[0,2048), waves 4-7 kv[2048,4096) ----
__global__ __launch_bounds__(512, 4) void k_attn(const short* __restrict__ q,
                                                 const short* __restrict__ k,
                                                 const short* __restrict__ vt,
                                                 short* __restrict__ ao){
  __shared__ union SM {
    short kv[2][2][64][72];                       // [group][K/V][row][col(+pad)]
    struct { float OB[4][16][64]; float mB[4][16]; float lB[4][16]; } cb;
  } sm;
  __shared__ short Ps[8][16][72];                 // per-wave P tile [q(16)][kv(64)]

  int blk = blockIdx.x;
  int q0 = (blk & 63) << 6;
  int bh = blk >> 6;
  const short* Qb = q  + (size_t)bh*NS*DK;
  const short* Kb = k  + (size_t)bh*NS*DK;
  const short* Vb = vt + (size_t)bh*DK*NS;
  int tid = threadIdx.x, lane = tid & 63, wid = tid >> 6;
  int l15 = lane & 15, lg = lane >> 4;
  int g  = wid >> 2;                              // kv half
  int wq = wid & 3;                               // q sub-tile (16 rows)
  int gtid = tid & 255;

  short8 aq[2];
  {
    // B-operand fragment: lane must hold k = (lane>>4)*8 + j  ->  + lg*8 (R1/R2 bug: this was missing)
    const short* qrow = Qb + (size_t)(q0 + wq*16 + l15)*DK + lg*8;
    aq[0] = *(const short8*)(qrow);
    aq[1] = *(const short8*)(qrow + 32);
  }
  const f32x4 fz = {0.f,0.f,0.f,0.f};
  f32x4 acc[4];
  for (int i=0;i<4;i++) acc[i] = fz;
  float mrun = -1e30f, lrun = 0.f;                // state for q-row (l15), log2 domain

  for (int t = 0; t < 32; ++t){
    int kv0 = g*2048 + t*64;
    __syncthreads();
    for (int it = 0; it < 2; ++it){
      int c = it*256 + gtid;
      int r = c >> 3, col = (c & 7) << 3;
      *(short8*)&sm.kv[g][0][r][col] = *(const short8*)&Kb[(size_t)(kv0 + r)*DK + col];
      *(short8*)&sm.kv[g][1][r][col] = *(const short8*)&Vb[(size_t)r*NS + kv0 + col];
    }
    __syncthreads();
    // S^T[kv, q] = mfma(K, Q): lane owns q = l15, kv = nf*16 + lg*4 + r
    f32x4 st[4];
    for (int nf=0;nf<4;nf++) st[nf] = fz;
    for (int kk=0;kk<2;kk++)
      for (int nf=0;nf<4;nf++){
        short8 bk = *(const short8*)&sm.kv[g][0][nf*16 + l15][kk*32 + lg*8];
        st[nf] = __builtin_amdgcn_mfma_f32_16x16x32_bf16(bk, aq[kk], st[nf], 0,0,0);
      }
    // row max: 16 regs, then across the 4 lanes sharing l15
    float mx = fmaxf(fmaxf(st[0][0],st[0][1]), fmaxf(st[0][2],st[0][3]));
    for (int nf=1;nf<4;nf++)
      mx = fmaxf(mx, fmaxf(fmaxf(st[nf][0],st[nf][1]), fmaxf(st[nf][2],st[nf][3])));
    mx = fmaxf(mx, __shfl_xor(mx, 16));
    mx = fmaxf(mx, __shfl_xor(mx, 32));
    float mnew = fmaxf(mrun, mx);
    float corr = ex2(mrun - mnew);
    mrun = mnew;
    float ps = 0.f;
    for (int nf=0;nf<4;nf++){
      float p0 = ex2(st[nf][0]-mnew), p1 = ex2(st[nf][1]-mnew);
      float p2 = ex2(st[nf][2]-mnew), p3 = ex2(st[nf][3]-mnew);
      ps += (p0+p1)+(p2+p3);
      uint2v pk = { cvtpk(p0,p1), cvtpk(p2,p3) };
      *(uint2v*)&Ps[wid][l15][nf*16 + lg*4] = pk;   // wave-private tile
    }
    // compiler fence: P stores (uint2v) and fragment reads (short8) are
    // distinct TBAA types; prevent ds_read hoisting above ds_write.
    asm volatile("" ::: "memory");
    ps += __shfl_xor(ps, 16);
    ps += __shfl_xor(ps, 32);
    lrun = lrun*corr + ps;
    // rescale acc (rows q = lg*4+r): fetch corr from lane l15==qloc
    for (int r=0;r<4;r++){
      float cv = __shfl(corr, lg*4 + r);
      for (int nf=0;nf<4;nf++) acc[nf][r] *= cv;
    }
    // PV: O[q, d] += P * V^T
    short8 ap0 = *(const short8*)&Ps[wid][l15][lg*8];
    short8 ap1 = *(const short8*)&Ps[wid][l15][32 + lg*8];
    for (int nf=0;nf<4;nf++){
      short8 bv0 = *(const short8*)&sm.kv[g][1][nf*16 + l15][lg*8];
      short8 bv1 = *(const short8*)&sm.kv[g][1][nf*16 + l15][32 + lg*8];
      acc[nf] = __builtin_amdgcn_mfma_f32_16x16x32_bf16(ap0, bv0, acc[nf], 0,0,0);
      acc[nf] = __builtin_amdgcn_mfma_f32_16x16x32_bf16(ap1, bv1, acc[nf], 0,0,0);
    }
  }

  // merge the two kv halves and write
  __syncthreads();
  if (g == 1){
    for (int nf=0;nf<4;nf++)
      for (int r=0;r<4;r++)
        sm.cb.OB[wq][lg*4 + r][nf*16 + l15] = acc[nf][r];
    if (lg == 0){ sm.cb.mB[wq][l15] = mrun; sm.cb.lB[wq][l15] = lrun; }
  }
  __syncthreads();
  if (g == 0){
    int b_ = bh >> 2, hh = bh & 3;
    for (int r=0;r<4;r++){
      int qloc = lg*4 + r;
      float mA = __shfl(mrun, qloc);
      float lA = __shfl(lrun, qloc);
      float mBv = sm.cb.mB[wq][qloc];
      float lBv = sm.cb.lB[wq][qloc];
      float M  = fmaxf(mA, mBv);
      float eA = ex2(mA - M), eB = ex2(mBv - M);
      float inv = 1.f/(eA*lA + eB*lBv);
      int s = q0 + wq*16 + qloc;
      for (int nf=0;nf<4;nf++){
        float val = (acc[nf][r]*eA + sm.cb.OB[wq][qloc][nf*16 + l15]*eB)*inv;
        ao[((size_t)b_*NS + s)*NC + hh*DK + nf*16 + l15] = f2bf(val);
      }
    }
  }
}

// ---- K6: out GEMM + bias + residual ----
__global__ __launch_bounds__(256) void k_out(const short* __restrict__ aoin,
                                             const short* __restrict__ wb,
                                             const float* __restrict__ ob,
                                             const float* __restrict__ x,
                                             float* __restrict__ out){
  __shared__ short As[128][40];
  __shared__ short Bs[128][40];
  int m0 = blockIdx.x << 7;
  int n0 = blockIdx.y << 7;
  int tid = threadIdx.x;
  int lane = tid & 63, wid = tid >> 6;
  int wm = (wid >> 1) << 6, wn = (wid & 1) << 6;
  int l15 = lane & 15, lg = lane >> 4;
  const f32x4 fz = {0.f,0.f,0.f,0.f};
  f32x4 acc[4][4];
  for (int i=0;i<4;i++) for(int j=0;j<4;j++) acc[i][j] = fz;
  for (int k0 = 0; k0 < NC; k0 += 32){
    __syncthreads();
    for (int it = 0; it < 2; ++it){
      int c = it*256 + tid;
      int r = c >> 2, kk8 = (c & 3) << 3;
      *(short8*)&As[r][kk8] = *(const short8*)&aoin[((size_t)(m0 + r))*NC + k0 + kk8];
      *(short8*)&Bs[r][kk8] = *(const short8*)&wb  [((size_t)(n0 + r))*NC + k0 + kk8];
    }
    __syncthreads();
    short8 a[4], b[4];
    for (int mf=0; mf<4; ++mf) a[mf] = *(const short8*)&As[wm + mf*16 + l15][lg*8];
    for (int nf=0; nf<4; ++nf) b[nf] = *(const short8*)&Bs[wn + nf*16 + l15][lg*8];
    for (int mf=0; mf<4; ++mf)
      for (int nf=0; nf<4; ++nf)
        acc[mf][nf] = __builtin_amdgcn_mfma_f32_16x16x32_bf16(a[mf], b[nf], acc[mf][nf], 0,0,0);
  }
  for (int mf=0; mf<4; ++mf)
    for (int nf=0; nf<4; ++nf)
      for (int r=0; r<4; ++r){
        int m = m0 + wm + mf*16 + lg*4 + r;
        int o = n0 + wn + nf*16 + l15;
        int b_ = m >> 12, s = m & 4095;
        size_t idx = ((size_t)b_*NC + o)*NS + s;
        out[idx] = acc[mf][nf][r] + ob[o] + x[idx];
      }
}

extern "C" void kernel_launch(void* const* d_in, const int* in_sizes, int n_in,
                              void* d_out, int out_size, void* d_ws, size_t ws_size,
                              hipStream_t stream){
  const float* x   = (const float*)d_in[0];
  const float* gnw = (const float*)d_in[1];
  const float* gnb = (const float*)d_in[2];
  const float* pw  = (const float*)d_in[3];
  const float* pb  = (const float*)d_in[4];
  const float* ow  = (const float*)d_in[5];
  const float* ob  = (const float*)d_in[6];
  float* out = (float*)d_out;

  char* ws = (char*)d_ws;
  float* mean = (float*)ws;
  float* rstd = mean + 64;
  short* wqkv = (short*)(ws + 512);
  short* wout = wqkv + NQKV*NC;
  short* h    = wout + NC*NC;
  short* qb   = h   + (size_t)NB*NS*NC;
  short* kb   = qb  + (size_t)NB*NH*NS*DK;
  short* vtb  = kb  + (size_t)NB*NH*NS*DK;
  short* ao   = vtb + (size_t)NB*NH*NS*DK;

  k_gnstats<<<64, 256, 0, stream>>>(x, mean, rstd);
  k_cvtw<<<768, 256, 0, stream>>>(pw, ow, wqkv, wout);
  k_gnapply<<<128, 256, 0, stream>>>(x, gnw, gnb, mean, rstd, h);
  k_qkv<<<dim3(64, 6), 256, 0, stream>>>(h, wqkv, pb, qb, kb, vtb);
  k_attn<<<512, 512, 0, stream>>>(qb, kb, vtb, ao);
  k_out<<<dim3(64, 2), 256, 0, stream>>>(ao, wout, ob, x, out);
}

// Round 5
// 169.772 us; speedup vs baseline: 1.5352x; 1.5352x over previous
//
#include <hip/hip_runtime.h>
#include <math.h>

#define NB 2
#define NC 256
#define NS 4096
#define NG 32
#define CPG 8
#define NH 4
#define DK 64
#define NQKV 768
#define QS 0.18033688011112042f   /* 0.125 * log2(e): folds attn scale + exp->exp2 */

typedef __attribute__((ext_vector_type(8))) short short8;
typedef __attribute__((ext_vector_type(4))) float f32x4;
typedef __attribute__((ext_vector_type(16))) float f32x16;
typedef __attribute__((ext_vector_type(4))) unsigned uint4v;

union U8 { uint4v u; short8 s; };

__device__ __forceinline__ short f2bf(float f){
  union { float f; unsigned u; } v; v.f = f;
  unsigned r = v.u + 0x7fffu + ((v.u >> 16) & 1u);
  return (short)(r >> 16);
}
__device__ __forceinline__ float ex2(float x){          // hardware 2^x
  float y; asm("v_exp_f32 %0, %1" : "=v"(y) : "v"(x)); return y;
}
__device__ __forceinline__ unsigned cvtpk(float lo, float hi){ // bf16(lo)|bf16(hi)<<16, RNE
  unsigned u; asm("v_cvt_pk_bf16_f32 %0, %1, %2" : "=v"(u) : "v"(lo), "v"(hi)); return u;
}
// x' (lanes>=32) <- y[lane-32]; y' (lanes<32) <- x[lane+32]; other halves unchanged
__device__ __forceinline__ void pl32swap(unsigned &x, unsigned &y){
  asm("v_permlane32_swap_b32 %0, %1" : "+v"(x), "+v"(y));
}

// ---- K1: group-norm stats ----
__global__ __launch_bounds__(256) void k_gnstats(const float* __restrict__ x,
                                                 float* __restrict__ mean,
                                                 float* __restrict__ rstd){
  int bg = blockIdx.x;
  const float* base = x + (size_t)bg * (CPG*NS);
  float s = 0.f, ss = 0.f;
  for (int i = threadIdx.x; i < CPG*NS; i += 256){
    float v = base[i]; s += v; ss += v*v;
  }
  for (int o = 32; o > 0; o >>= 1){ s += __shfl_down(s, o); ss += __shfl_down(ss, o); }
  __shared__ float red[8];
  int w = threadIdx.x >> 6;
  if ((threadIdx.x & 63) == 0){ red[w] = s; red[4+w] = ss; }
  __syncthreads();
  if (threadIdx.x == 0){
    float S  = red[0]+red[1]+red[2]+red[3];
    float SS = red[4]+red[5]+red[6]+red[7];
    const float inv = 1.f/(float)(CPG*NS);
    float m = S*inv; float var = SS*inv - m*m;
    mean[bg] = m; rstd[bg] = rsqrtf(var + 1e-5f);
  }
}

// ---- K2: normalize + transpose [B,C,S] -> h[B,S,C] bf16 ----
__global__ __launch_bounds__(256) void k_gnapply(const float* __restrict__ x,
                                                 const float* __restrict__ gw,
                                                 const float* __restrict__ gb,
                                                 const float* __restrict__ mean,
                                                 const float* __restrict__ rstd,
                                                 short* __restrict__ h){
  __shared__ short tile[64][258];
  int b  = blockIdx.x >> 6;
  int s0 = (blockIdx.x & 63) << 6;
  int sl = threadIdx.x & 63;
  int c0 = threadIdx.x >> 6;
  for (int ci = 0; ci < NC; ci += 4){
    int c = ci + c0;
    int sg = (b << 5) + (c >> 3);
    float v  = x[((size_t)b*NC + c)*NS + s0 + sl];
    float hn = (v - mean[sg]) * rstd[sg] * gw[c] + gb[c];
    tile[sl][c] = f2bf(hn);
  }
  __syncthreads();
  for (int it = 0; it < 32; ++it){
    int idx = it*256 + threadIdx.x;
    int row = idx >> 7, col = (idx & 127) << 1;
    unsigned p = ((unsigned)(unsigned short)tile[row][col]) |
                 (((unsigned)(unsigned short)tile[row][col+1]) << 16);
    *(unsigned*)&h[((size_t)b*NS + s0 + row)*NC + col] = p;
  }
}

// ---- K3: weights f32 -> bf16 ----
__global__ __launch_bounds__(256) void k_cvtw(const float* __restrict__ pw,
                                              const float* __restrict__ ow,
                                              short* __restrict__ pwb,
                                              short* __restrict__ owb){
  int i = blockIdx.x*256 + threadIdx.x;
  if (i < NQKV*NC) pwb[i] = f2bf(pw[i]);
  if (i < NC*NC)   owb[i] = f2bf(ow[i]);
}

// ---- K4: QKV GEMM with scatter epilogue; q gets QS scale folded in ----
__global__ __launch_bounds__(256) void k_qkv(const short* __restrict__ h,
                                             const short* __restrict__ wb,
                                             const float* __restrict__ pb,
                                             short* __restrict__ qo,
                                             short* __restrict__ ko,
                                             short* __restrict__ vto){
  __shared__ short As[128][40];
  __shared__ short Bs[128][40];
  int m0 = blockIdx.x << 7;
  int n0 = blockIdx.y << 7;
  int tid = threadIdx.x;
  int lane = tid & 63, wid = tid >> 6;
  int wm = (wid >> 1) << 6, wn = (wid & 1) << 6;
  int l15 = lane & 15, lg = lane >> 4;
  const f32x4 fz = {0.f,0.f,0.f,0.f};
  f32x4 acc[4][4];
  for (int i=0;i<4;i++) for(int j=0;j<4;j++) acc[i][j] = fz;
  for (int k0 = 0; k0 < NC; k0 += 32){
    __syncthreads();
    for (int it = 0; it < 2; ++it){
      int c = it*256 + tid;
      int r = c >> 2, kk8 = (c & 3) << 3;
      *(short8*)&As[r][kk8] = *(const short8*)&h [((size_t)(m0 + r))*NC + k0 + kk8];
      *(short8*)&Bs[r][kk8] = *(const short8*)&wb[((size_t)(n0 + r))*NC + k0 + kk8];
    }
    __syncthreads();
    short8 a[4], b[4];
    for (int mf=0; mf<4; ++mf) a[mf] = *(const short8*)&As[wm + mf*16 + l15][lg*8];
    for (int nf=0; nf<4; ++nf) b[nf] = *(const short8*)&Bs[wn + nf*16 + l15][lg*8];
    for (int mf=0; mf<4; ++mf)
      for (int nf=0; nf<4; ++nf)
        acc[mf][nf] = __builtin_amdgcn_mfma_f32_16x16x32_bf16(a[mf], b[nf], acc[mf][nf], 0,0,0);
  }
  for (int mf=0; mf<4; ++mf)
    for (int nf=0; nf<4; ++nf)
      for (int r=0; r<4; ++r){
        int m = m0 + wm + mf*16 + lg*4 + r;
        int o = n0 + wn + nf*16 + l15;
        float val = acc[mf][nf][r] + pb[o];
        int b_ = m >> 12, s = m & 4095;
        int hh = o / 192, rem = o - hh*192;
        int t = rem >> 6, d = rem & 63;
        size_t bh = (size_t)(b_*NH + hh);
        if (t == 0)      qo [(bh*NS + s)*DK + d] = f2bf(val * QS);
        else if (t == 1) ko [(bh*NS + s)*DK + d] = f2bf(val);
        else             vto[(bh*DK + d)*NS + s] = f2bf(val);
      }
}

// ---- K5: flash attention, 32x32 MFMA, register-P, 8 waves (2 kv-groups x 4 q-subtiles) ----
// block = 128 q-rows; wave = 32 q-rows; per-lane state is q-column l31.
__global__ __launch_bounds__(512, 2) void k_attn(const short* __restrict__ q,
                                                 const short* __restrict__ k,
                                                 const short* __restrict__ vt,
                                                 short* __restrict__ ao){
  __shared__ union SM {
    short kv[2][2][64][72];   // [group][K=0/V^T=1][row][col(+pad 8)]
    struct { float OB[4][64][33]; float mB[4][32]; float lB[4][32]; } cb;
  } sm;

  int blk = blockIdx.x;
  int q0 = (blk & 31) << 7;          // 32 q-blocks of 128
  int bh = blk >> 5;
  const short* Qb = q  + (size_t)bh*NS*DK;
  const short* Kb = k  + (size_t)bh*NS*DK;
  const short* Vb = vt + (size_t)bh*DK*NS;
  int tid = threadIdx.x, lane = tid & 63, wid = tid >> 6;
  int l31 = lane & 31, hi = lane >> 5;
  int g = wid >> 2, wq = wid & 3;
  int gtid = tid & 255;

  // Q regs (B-frag): bq[step] = Q[q = q0+wq*32+l31][d = step*16 + hi*8 .. +7]
  short8 bq[4];
  {
    const short* qrow = Qb + (size_t)(q0 + wq*32 + l31)*DK + hi*8;
    #pragma unroll
    for (int s2 = 0; s2 < 4; ++s2) bq[s2] = *(const short8*)(qrow + s2*16);
  }

  f32x16 ot0, ot1;                    // O^T acc: [d-half][reg]; col q = l31
  #pragma unroll
  for (int i = 0; i < 16; ++i){ ot0[i] = 0.f; ot1[i] = 0.f; }
  float mrun = -1e30f, lrun = 0.f;    // per-q (l31), log2 domain

  short8 kpre[2], vpre[2];
  {
    int kv0 = g*2048;
    #pragma unroll
    for (int it = 0; it < 2; ++it){
      int c = it*256 + gtid, r = c >> 3, col = (c & 7) << 3;
      kpre[it] = *(const short8*)&Kb[(size_t)(kv0 + r)*DK + col];
      vpre[it] = *(const short8*)&Vb[(size_t)r*NS + kv0 + col];
    }
  }

  for (int t = 0; t < 32; ++t){
    __syncthreads();
    #pragma unroll
    for (int it = 0; it < 2; ++it){
      int c = it*256 + gtid, r = c >> 3, col = (c & 7) << 3;
      *(short8*)&sm.kv[g][0][r][col] = kpre[it];
      *(short8*)&sm.kv[g][1][r][col] = vpre[it];
    }
    __syncthreads();
    if (t < 31){                      // prefetch next tile; hides HBM under compute
      int kv0 = g*2048 + (t+1)*64;
      #pragma unroll
      for (int it = 0; it < 2; ++it){
        int c = it*256 + gtid, r = c >> 3, col = (c & 7) << 3;
        kpre[it] = *(const short8*)&Kb[(size_t)(kv0 + r)*DK + col];
        vpre[it] = *(const short8*)&Vb[(size_t)r*NS + kv0 + col];
      }
    }
    // S^T[kv][q] = K x Q : A = K[kv row=l31(+32)][k chunk], B = Q (regs)
    f32x16 st0, st1;
    #pragma unroll
    for (int i = 0; i < 16; ++i){ st0[i] = 0.f; st1[i] = 0.f; }
    #pragma unroll
    for (int s2 = 0; s2 < 4; ++s2){
      short8 ka0 = *(const short8*)&sm.kv[g][0][l31     ][s2*16 + hi*8];
      short8 ka1 = *(const short8*)&sm.kv[g][0][32 + l31][s2*16 + hi*8];
      st0 = __builtin_amdgcn_mfma_f32_32x32x16_bf16(ka0, bq[s2], st0, 0,0,0);
      st1 = __builtin_amdgcn_mfma_f32_32x32x16_bf16(ka1, bq[s2], st1, 0,0,0);
    }
    // online softmax for q = l31 (lane^32 holds the other 32 kv rows)
    float mx = -1e30f;
    #pragma unroll
    for (int i = 0; i < 16; ++i) mx = fmaxf(mx, fmaxf(st0[i], st1[i]));
    mx = fmaxf(mx, __shfl_xor(mx, 32));
    float mnew = fmaxf(mrun, mx);
    float corr = ex2(mrun - mnew);
    float p0[16], p1[16]; float ps = 0.f;
    #pragma unroll
    for (int i = 0; i < 16; ++i){
      p0[i] = ex2(st0[i] - mnew); p1[i] = ex2(st1[i] - mnew);
      ps += p0[i] + p1[i];
    }
    ps += __shfl_xor(ps, 32);
    lrun = lrun*corr + ps; mrun = mnew;
    #pragma unroll
    for (int i = 0; i < 16; ++i){ ot0[i] *= corr; ot1[i] *= corr; }
    // pack P (kv rows, own q col) -> PV B-frags via cvt_pk + permlane32_swap
    // lane holds P[kv = 32*kvh + 8a + 4hi + b][q=l31]; frag needs kv = 16*i2 + 8hi + j
    unsigned pk0[8], pk1[8];
    #pragma unroll
    for (int a = 0; a < 4; ++a){
      pk0[a]     = cvtpk(p0[4*a+0], p0[4*a+1]);
      pk1[a]     = cvtpk(p0[4*a+2], p0[4*a+3]);
      pk0[4 + a] = cvtpk(p1[4*a+0], p1[4*a+1]);
      pk1[4 + a] = cvtpk(p1[4*a+2], p1[4*a+3]);
    }
    #pragma unroll
    for (int i2 = 0; i2 < 4; ++i2){
      unsigned w0 = pk0[2*i2], w2 = pk0[2*i2+1]; pl32swap(w0, w2);
      unsigned w1 = pk1[2*i2], w3 = pk1[2*i2+1]; pl32swap(w1, w3);
      U8 cv; cv.u = (uint4v){w0, w1, w2, w3};
      short8 av0 = *(const short8*)&sm.kv[g][1][l31     ][i2*16 + hi*8];
      short8 av1 = *(const short8*)&sm.kv[g][1][32 + l31][i2*16 + hi*8];
      ot0 = __builtin_amdgcn_mfma_f32_32x32x16_bf16(av0, cv.s, ot0, 0,0,0);
      ot1 = __builtin_amdgcn_mfma_f32_32x32x16_bf16(av1, cv.s, ot1, 0,0,0);
    }
  }

  // merge kv-groups through LDS (overlay; KV dead after barrier)
  __syncthreads();
  if (g == 1){
    #pragma unroll
    for (int r2 = 0; r2 < 16; ++r2){
      int dl = (r2 & 3) + 8*(r2 >> 2) + 4*hi;
      sm.cb.OB[wq][dl][l31]      = ot0[r2];
      sm.cb.OB[wq][32 + dl][l31] = ot1[r2];
    }
    if (hi == 0){ sm.cb.mB[wq][l31] = mrun; sm.cb.lB[wq][l31] = lrun; }
  }
  __syncthreads();
  if (g == 0){
    float mBv = sm.cb.mB[wq][l31], lBv = sm.cb.lB[wq][l31];
    float M  = fmaxf(mrun, mBv);
    float eA = ex2(mrun - M), eB = ex2(mBv - M);
    float inv = 1.f/(eA*lrun + eB*lBv);
    eA *= inv; eB *= inv;
    #pragma unroll
    for (int r2 = 0; r2 < 16; ++r2){
      int dl = (r2 & 3) + 8*(r2 >> 2) + 4*hi;
      sm.cb.OB[wq][dl][l31]      = ot0[r2]*eA + sm.cb.OB[wq][dl][l31]*eB;
      sm.cb.OB[wq][32 + dl][l31] = ot1[r2]*eA + sm.cb.OB[wq][32 + dl][l31]*eB;
    }
  }
  __syncthreads();
  // cooperative coalesced writeout: thread -> (q row, 16-d chunk)
  {
    int ql = tid >> 2, dc = (tid & 3) << 4;
    int b_ = bh >> 2, hh = bh & 3;
    float v2[16];
    #pragma unroll
    for (int i = 0; i < 16; ++i) v2[i] = sm.cb.OB[ql >> 5][dc + i][ql & 31];
    uint4v wa = { cvtpk(v2[0],v2[1]),  cvtpk(v2[2],v2[3]),
                  cvtpk(v2[4],v2[5]),  cvtpk(v2[6],v2[7]) };
    uint4v wb2 = { cvtpk(v2[8],v2[9]),   cvtpk(v2[10],v2[11]),
                   cvtpk(v2[12],v2[13]), cvtpk(v2[14],v2[15]) };
    size_t base = ((size_t)b_*NS + q0 + ql)*NC + hh*DK + dc;
    *(uint4v*)&ao[base]     = wa;
    *(uint4v*)&ao[base + 8] = wb2;
  }
}

// ---- K6: out GEMM + bias + residual ----
__global__ __launch_bounds__(256) void k_out(const short* __restrict__ aoin,
                                             const short* __restrict__ wb,
                                             const float* __restrict__ ob,
                                             const float* __restrict__ x,
                                             float* __restrict__ out){
  __shared__ short As[128][40];
  __shared__ short Bs[128][40];
  int m0 = blockIdx.x << 7;
  int n0 = blockIdx.y << 7;
  int tid = threadIdx.x;
  int lane = tid & 63, wid = tid >> 6;
  int wm = (wid >> 1) << 6, wn = (wid & 1) << 6;
  int l15 = lane & 15, lg = lane >> 4;
  const f32x4 fz = {0.f,0.f,0.f,0.f};
  f32x4 acc[4][4];
  for (int i=0;i<4;i++) for(int j=0;j<4;j++) acc[i][j] = fz;
  for (int k0 = 0; k0 < NC; k0 += 32){
    __syncthreads();
    for (int it = 0; it < 2; ++it){
      int c = it*256 + tid;
      int r = c >> 2, kk8 = (c & 3) << 3;
      *(short8*)&As[r][kk8] = *(const short8*)&aoin[((size_t)(m0 + r))*NC + k0 + kk8];
      *(short8*)&Bs[r][kk8] = *(const short8*)&wb  [((size_t)(n0 + r))*NC + k0 + kk8];
    }
    __syncthreads();
    short8 a[4], b[4];
    for (int mf=0; mf<4; ++mf) a[mf] = *(const short8*)&As[wm + mf*16 + l15][lg*8];
    for (int nf=0; nf<4; ++nf) b[nf] = *(const short8*)&Bs[wn + nf*16 + l15][lg*8];
    for (int mf=0; mf<4; ++mf)
      for (int nf=0; nf<4; ++nf)
        acc[mf][nf] = __builtin_amdgcn_mfma_f32_16x16x32_bf16(a[mf], b[nf], acc[mf][nf], 0,0,0);
  }
  for (int mf=0; mf<4; ++mf)
    for (int nf=0; nf<4; ++nf)
      for (int r=0; r<4; ++r){
        int m = m0 + wm + mf*16 + lg*4 + r;
        int o = n0 + wn + nf*16 + l15;
        int b_ = m >> 12, s = m & 4095;
        size_t idx = ((size_t)b_*NC + o)*NS + s;
        out[idx] = acc[mf][nf][r] + ob[o] + x[idx];
      }
}

extern "C" void kernel_launch(void* const* d_in, const int* in_sizes, int n_in,
                              void* d_out, int out_size, void* d_ws, size_t ws_size,
                              hipStream_t stream){
  const float* x   = (const float*)d_in[0];
  const float* gnw = (const float*)d_in[1];
  const float* gnb = (const float*)d_in[2];
  const float* pw  = (const float*)d_in[3];
  const float* pb  = (const float*)d_in[4];
  const float* ow  = (const float*)d_in[5];
  const float* ob  = (const float*)d_in[6];
  float* out = (float*)d_out;

  char* ws = (char*)d_ws;
  float* mean = (float*)ws;
  float* rstd = mean + 64;
  short* wqkv = (short*)(ws + 512);
  short* wout = wqkv + NQKV*NC;
  short* h    = wout + NC*NC;
  short* qb   = h   + (size_t)NB*NS*NC;
  short* kb   = qb  + (size_t)NB*NH*NS*DK;
  short* vtb  = kb  + (size_t)NB*NH*NS*DK;
  short* ao   = vtb + (size_t)NB*NH*NS*DK;

  k_gnstats<<<64, 256, 0, stream>>>(x, mean, rstd);
  k_cvtw<<<768, 256, 0, stream>>>(pw, ow, wqkv, wout);
  k_gnapply<<<128, 256, 0, stream>>>(x, gnw, gnb, mean, rstd, h);
  k_qkv<<<dim3(64, 6), 256, 0, stream>>>(h, wqkv, pb, qb, kb, vtb);
  k_attn<<<256, 512, 0, stream>>>(qb, kb, vtb, ao);
  k_out<<<dim3(64, 2), 256, 0, stream>>>(ao, wout, ob, x, out);
}

// Round 6
// 130.373 us; speedup vs baseline: 1.9992x; 1.3022x over previous
//
#include <hip/hip_runtime.h>
#include <math.h>

#define NB 2
#define NC 256
#define NS 4096
#define NG 32
#define CPG 8
#define NH 4
#define DK 64
#define NQKV 768
#define NKG 4      /* kv groups in k_attn */
#define TPG 16     /* tiles (of 64 kv) per group */
#define QS 0.18033688011112042f   /* 0.125 * log2(e): folds attn scale + exp->exp2 */

typedef __attribute__((ext_vector_type(8))) short short8;
typedef __attribute__((ext_vector_type(4))) float f32x4;
typedef __attribute__((ext_vector_type(16))) float f32x16;
typedef __attribute__((ext_vector_type(4))) unsigned uint4v;

union U8 { uint4v u; short8 s; };

__device__ __forceinline__ short f2bf(float f){
  union { float f; unsigned u; } v; v.f = f;
  unsigned r = v.u + 0x7fffu + ((v.u >> 16) & 1u);
  return (short)(r >> 16);
}
__device__ __forceinline__ float ex2(float x){          // hardware 2^x
  float y; asm("v_exp_f32 %0, %1" : "=v"(y) : "v"(x)); return y;
}
__device__ __forceinline__ unsigned cvtpk(float lo, float hi){ // bf16(lo)|bf16(hi)<<16, RNE
  unsigned u; asm("v_cvt_pk_bf16_f32 %0, %1, %2" : "=v"(u) : "v"(lo), "v"(hi)); return u;
}
// x' (lanes>=32) <- y[lane-32]; y' (lanes<32) <- x[lane+32]
__device__ __forceinline__ void pl32swap(unsigned &x, unsigned &y){
  asm("v_permlane32_swap_b32 %0, %1" : "+v"(x), "+v"(y));
}

// ---- K1: group-norm stats ----
__global__ __launch_bounds__(256) void k_gnstats(const float* __restrict__ x,
                                                 float* __restrict__ mean,
                                                 float* __restrict__ rstd){
  int bg = blockIdx.x;
  const float* base = x + (size_t)bg * (CPG*NS);
  float s = 0.f, ss = 0.f;
  for (int i = threadIdx.x; i < CPG*NS; i += 256){
    float v = base[i]; s += v; ss += v*v;
  }
  for (int o = 32; o > 0; o >>= 1){ s += __shfl_down(s, o); ss += __shfl_down(ss, o); }
  __shared__ float red[8];
  int w = threadIdx.x >> 6;
  if ((threadIdx.x & 63) == 0){ red[w] = s; red[4+w] = ss; }
  __syncthreads();
  if (threadIdx.x == 0){
    float S  = red[0]+red[1]+red[2]+red[3];
    float SS = red[4]+red[5]+red[6]+red[7];
    const float inv = 1.f/(float)(CPG*NS);
    float m = S*inv; float var = SS*inv - m*m;
    mean[bg] = m; rstd[bg] = rsqrtf(var + 1e-5f);
  }
}

// ---- K2: normalize + transpose [B,C,S] -> h[B,S,C] bf16 ----
__global__ __launch_bounds__(256) void k_gnapply(const float* __restrict__ x,
                                                 const float* __restrict__ gw,
                                                 const float* __restrict__ gb,
                                                 const float* __restrict__ mean,
                                                 const float* __restrict__ rstd,
                                                 short* __restrict__ h){
  __shared__ short tile[64][258];
  int b  = blockIdx.x >> 6;
  int s0 = (blockIdx.x & 63) << 6;
  int sl = threadIdx.x & 63;
  int c0 = threadIdx.x >> 6;
  for (int ci = 0; ci < NC; ci += 4){
    int c = ci + c0;
    int sg = (b << 5) + (c >> 3);
    float v  = x[((size_t)b*NC + c)*NS + s0 + sl];
    float hn = (v - mean[sg]) * rstd[sg] * gw[c] + gb[c];
    tile[sl][c] = f2bf(hn);
  }
  __syncthreads();
  for (int it = 0; it < 32; ++it){
    int idx = it*256 + threadIdx.x;
    int row = idx >> 7, col = (idx & 127) << 1;
    unsigned p = ((unsigned)(unsigned short)tile[row][col]) |
                 (((unsigned)(unsigned short)tile[row][col+1]) << 16);
    *(unsigned*)&h[((size_t)b*NS + s0 + row)*NC + col] = p;
  }
}

// ---- K3: weights f32 -> bf16 ----
__global__ __launch_bounds__(256) void k_cvtw(const float* __restrict__ pw,
                                              const float* __restrict__ ow,
                                              short* __restrict__ pwb,
                                              short* __restrict__ owb){
  int i = blockIdx.x*256 + threadIdx.x;
  if (i < NQKV*NC) pwb[i] = f2bf(pw[i]);
  if (i < NC*NC)   owb[i] = f2bf(ow[i]);
}

// ---- K4: QKV GEMM with scatter epilogue; q gets QS scale folded in ----
__global__ __launch_bounds__(256) void k_qkv(const short* __restrict__ h,
                                             const short* __restrict__ wb,
                                             const float* __restrict__ pb,
                                             short* __restrict__ qo,
                                             short* __restrict__ ko,
                                             short* __restrict__ vto){
  __shared__ short As[128][40];
  __shared__ short Bs[128][40];
  int m0 = blockIdx.x << 7;
  int n0 = blockIdx.y << 7;
  int tid = threadIdx.x;
  int lane = tid & 63, wid = tid >> 6;
  int wm = (wid >> 1) << 6, wn = (wid & 1) << 6;
  int l15 = lane & 15, lg = lane >> 4;
  const f32x4 fz = {0.f,0.f,0.f,0.f};
  f32x4 acc[4][4];
  for (int i=0;i<4;i++) for(int j=0;j<4;j++) acc[i][j] = fz;
  for (int k0 = 0; k0 < NC; k0 += 32){
    __syncthreads();
    for (int it = 0; it < 2; ++it){
      int c = it*256 + tid;
      int r = c >> 2, kk8 = (c & 3) << 3;
      *(short8*)&As[r][kk8] = *(const short8*)&h [((size_t)(m0 + r))*NC + k0 + kk8];
      *(short8*)&Bs[r][kk8] = *(const short8*)&wb[((size_t)(n0 + r))*NC + k0 + kk8];
    }
    __syncthreads();
    short8 a[4], b[4];
    for (int mf=0; mf<4; ++mf) a[mf] = *(const short8*)&As[wm + mf*16 + l15][lg*8];
    for (int nf=0; nf<4; ++nf) b[nf] = *(const short8*)&Bs[wn + nf*16 + l15][lg*8];
    for (int mf=0; mf<4; ++mf)
      for (int nf=0; nf<4; ++nf)
        acc[mf][nf] = __builtin_amdgcn_mfma_f32_16x16x32_bf16(a[mf], b[nf], acc[mf][nf], 0,0,0);
  }
  for (int mf=0; mf<4; ++mf)
    for (int nf=0; nf<4; ++nf)
      for (int r=0; r<4; ++r){
        int m = m0 + wm + mf*16 + lg*4 + r;
        int o = n0 + wn + nf*16 + l15;
        float val = acc[mf][nf][r] + pb[o];
        int b_ = m >> 12, s = m & 4095;
        int hh = o / 192, rem = o - hh*192;
        int t = rem >> 6, d = rem & 63;
        size_t bh = (size_t)(b_*NH + hh);
        if (t == 0)      qo [(bh*NS + s)*DK + d] = f2bf(val * QS);
        else if (t == 1) ko [(bh*NS + s)*DK + d] = f2bf(val);
        else             vto[(bh*DK + d)*NS + s] = f2bf(val);
      }
}

// ---- K5: flash attention, 32x32 MFMA, register-P, 16 waves (4 kv-groups x 4 q-subtiles),
//          double-buffered LDS (1 barrier/tile), defer-rescale ----
struct SMK { short kv[NKG][2][2][64][72]; };   // [group][buf][K/V][row][col+pad] = 147456 B
struct SMC {                                    // epilogue overlay (138240 B)
  float gOB[3][4][64][33];
  float ml[3][4][2][32];
  float fOB[4][64][33];
};

__global__ __launch_bounds__(1024, 4) void k_attn(const short* __restrict__ q,
                                                  const short* __restrict__ k,
                                                  const short* __restrict__ vt,
                                                  short* __restrict__ ao){
  extern __shared__ char smem[];
  SMK* sk = (SMK*)smem;
  SMC* sc = (SMC*)smem;

  int blk = blockIdx.x;
  int q0 = (blk & 31) << 7;          // 32 q-blocks of 128
  int bh = blk >> 5;
  const short* Qb = q  + (size_t)bh*NS*DK;
  const short* Kb = k  + (size_t)bh*NS*DK;
  const short* Vb = vt + (size_t)bh*DK*NS;
  int tid = threadIdx.x, lane = tid & 63, wid = tid >> 6;
  int l31 = lane & 31, hi = lane >> 5;
  int g = wid >> 2, wq = wid & 3;
  int gtid = tid & 255;
  int kvbase = g << 10;              // g*1024 kv rows

  // Q regs (B-frag): bq[s2] = Q[q = q0+wq*32+l31][d = s2*16 + hi*8 .. +7]
  short8 bq[4];
  {
    const short* qrow = Qb + (size_t)(q0 + wq*32 + l31)*DK + hi*8;
    #pragma unroll
    for (int s2 = 0; s2 < 4; ++s2) bq[s2] = *(const short8*)(qrow + s2*16);
  }

  f32x16 ot0, ot1;                    // O^T acc: [d-half][reg]; col q = l31
  #pragma unroll
  for (int i = 0; i < 16; ++i){ ot0[i] = 0.f; ot1[i] = 0.f; }
  float mrun = -1e30f, lrun = 0.f;    // per-q (l31), log2 domain

  // staging coords: c = it*256 + gtid -> row r, col (16B chunk)
  short8 kpre[2], vpre[2];
  #pragma unroll
  for (int it = 0; it < 2; ++it){    // tile 0 -> regs
    int c = it*256 + gtid, r = c >> 3, col = (c & 7) << 3;
    kpre[it] = *(const short8*)&Kb[(size_t)(kvbase + r)*DK + col];
    vpre[it] = *(const short8*)&Vb[(size_t)r*NS + kvbase + col];
  }
  #pragma unroll
  for (int it = 0; it < 2; ++it){    // tile 0 -> buf0 (no barrier yet; synced at loop top)
    int c = it*256 + gtid, r = c >> 3, col = (c & 7) << 3;
    *(short8*)&sk->kv[g][0][0][r][col] = kpre[it];
    *(short8*)&sk->kv[g][0][1][r][col] = vpre[it];
  }
  #pragma unroll
  for (int it = 0; it < 2; ++it){    // tile 1 -> regs
    int c = it*256 + gtid, r = c >> 3, col = (c & 7) << 3;
    kpre[it] = *(const short8*)&Kb[(size_t)(kvbase + 64 + r)*DK + col];
    vpre[it] = *(const short8*)&Vb[(size_t)r*NS + kvbase + 64 + col];
  }

  for (int t = 0; t < TPG; ++t){
    __syncthreads();                 // buf[(t+1)&1] free (tile t-1 done) + buf[t&1] ready
    if (t + 1 < TPG){
      int nb = (t + 1) & 1;
      #pragma unroll
      for (int it = 0; it < 2; ++it){
        int c = it*256 + gtid, r = c >> 3, col = (c & 7) << 3;
        *(short8*)&sk->kv[g][nb][0][r][col] = kpre[it];
        *(short8*)&sk->kv[g][nb][1][r][col] = vpre[it];
      }
    }
    if (t + 2 < TPG){
      int kv0 = kvbase + (t + 2)*64;
      #pragma unroll
      for (int it = 0; it < 2; ++it){
        int c = it*256 + gtid, r = c >> 3, col = (c & 7) << 3;
        kpre[it] = *(const short8*)&Kb[(size_t)(kv0 + r)*DK + col];
        vpre[it] = *(const short8*)&Vb[(size_t)r*NS + kv0 + col];
      }
    }
    const short (*Kl)[72] = sk->kv[g][t & 1][0];
    const short (*Vl)[72] = sk->kv[g][t & 1][1];
    // S^T[kv][q] = K x Q
    f32x16 st0, st1;
    #pragma unroll
    for (int i = 0; i < 16; ++i){ st0[i] = 0.f; st1[i] = 0.f; }
    const short* Kr0 = &Kl[l31][hi*8];
    const short* Kr1 = &Kl[32 + l31][hi*8];
    #pragma unroll
    for (int s2 = 0; s2 < 4; ++s2){
      short8 ka0 = *(const short8*)(Kr0 + s2*16);
      short8 ka1 = *(const short8*)(Kr1 + s2*16);
      st0 = __builtin_amdgcn_mfma_f32_32x32x16_bf16(ka0, bq[s2], st0, 0,0,0);
      st1 = __builtin_amdgcn_mfma_f32_32x32x16_bf16(ka1, bq[s2], st1, 0,0,0);
    }
    // online softmax for q = l31 (lane^32 holds the other 32 kv rows)
    float mx = -1e30f;
    #pragma unroll
    for (int i = 0; i < 16; ++i) mx = fmaxf(mx, fmaxf(st0[i], st1[i]));
    mx = fmaxf(mx, __shfl_xor(mx, 32));
    if (!__all(mx - mrun <= 8.f)){   // defer-rescale: P bounded by 2^8, bf16-safe
      float mnew = fmaxf(mrun, mx);
      float corr = ex2(mrun - mnew);
      lrun *= corr;
      #pragma unroll
      for (int i = 0; i < 16; ++i){ ot0[i] *= corr; ot1[i] *= corr; }
      mrun = mnew;
    }
    float p0[16], p1[16]; float ps = 0.f;
    #pragma unroll
    for (int i = 0; i < 16; ++i){
      p0[i] = ex2(st0[i] - mrun); p1[i] = ex2(st1[i] - mrun);
      ps += p0[i] + p1[i];
    }
    ps += __shfl_xor(ps, 32);
    lrun += ps;
    // pack P -> PV B-frags via cvt_pk + permlane32_swap; PV: O^T += V^T x P
    unsigned pk0[8], pk1[8];
    #pragma unroll
    for (int a = 0; a < 4; ++a){
      pk0[a]     = cvtpk(p0[4*a+0], p0[4*a+1]);
      pk1[a]     = cvtpk(p0[4*a+2], p0[4*a+3]);
      pk0[4 + a] = cvtpk(p1[4*a+0], p1[4*a+1]);
      pk1[4 + a] = cvtpk(p1[4*a+2], p1[4*a+3]);
    }
    const short* Vr0 = &Vl[l31][hi*8];
    const short* Vr1 = &Vl[32 + l31][hi*8];
    #pragma unroll
    for (int i2 = 0; i2 < 4; ++i2){
      unsigned w0 = pk0[2*i2], w2 = pk0[2*i2+1]; pl32swap(w0, w2);
      unsigned w1 = pk1[2*i2], w3 = pk1[2*i2+1]; pl32swap(w1, w3);
      U8 cv; cv.u = (uint4v){w0, w1, w2, w3};
      short8 av0 = *(const short8*)(Vr0 + i2*16);
      short8 av1 = *(const short8*)(Vr1 + i2*16);
      ot0 = __builtin_amdgcn_mfma_f32_32x32x16_bf16(av0, cv.s, ot0, 0,0,0);
      ot1 = __builtin_amdgcn_mfma_f32_32x32x16_bf16(av1, cv.s, ot1, 0,0,0);
    }
  }

  // ---- 4-way merge through LDS overlay ----
  __syncthreads();
  if (g > 0){
    #pragma unroll
    for (int r2 = 0; r2 < 16; ++r2){
      int dl = (r2 & 3) + 8*(r2 >> 2) + 4*hi;
      sc->gOB[g-1][wq][dl][l31]      = ot0[r2];
      sc->gOB[g-1][wq][32 + dl][l31] = ot1[r2];
    }
    if (hi == 0){ sc->ml[g-1][wq][0][l31] = mrun; sc->ml[g-1][wq][1][l31] = lrun; }
  }
  __syncthreads();
  if (g == 0){
    float m1 = sc->ml[0][wq][0][l31], l1 = sc->ml[0][wq][1][l31];
    float m2 = sc->ml[1][wq][0][l31], l2 = sc->ml[1][wq][1][l31];
    float m3 = sc->ml[2][wq][0][l31], l3 = sc->ml[2][wq][1][l31];
    float M  = fmaxf(fmaxf(mrun, m1), fmaxf(m2, m3));
    float w0 = ex2(mrun - M), w1 = ex2(m1 - M), w2 = ex2(m2 - M), w3 = ex2(m3 - M);
    float inv = 1.f/(lrun*w0 + l1*w1 + l2*w2 + l3*w3);
    w0 *= inv; w1 *= inv; w2 *= inv; w3 *= inv;
    #pragma unroll
    for (int r2 = 0; r2 < 16; ++r2){
      int dl = (r2 & 3) + 8*(r2 >> 2) + 4*hi;
      sc->fOB[wq][dl][l31] = ot0[r2]*w0 + sc->gOB[0][wq][dl][l31]*w1
                           + sc->gOB[1][wq][dl][l31]*w2 + sc->gOB[2][wq][dl][l31]*w3;
      sc->fOB[wq][32+dl][l31] = ot1[r2]*w0 + sc->gOB[0][wq][32+dl][l31]*w1
                              + sc->gOB[1][wq][32+dl][l31]*w2 + sc->gOB[2][wq][32+dl][l31]*w3;
    }
  }
  __syncthreads();
  // coalesced writeout: 1024 threads, thread -> (q row, 8-d chunk)
  {
    int ql = tid >> 3, dc = (tid & 7) << 3;
    int b_ = bh >> 2, hh = bh & 3;
    float v2[8];
    #pragma unroll
    for (int i = 0; i < 8; ++i) v2[i] = sc->fOB[ql >> 5][dc + i][ql & 31];
    uint4v wa = { cvtpk(v2[0],v2[1]), cvtpk(v2[2],v2[3]),
                  cvtpk(v2[4],v2[5]), cvtpk(v2[6],v2[7]) };
    size_t base = ((size_t)b_*NS + q0 + ql)*NC + hh*DK + dc;
    *(uint4v*)&ao[base] = wa;
  }
}

// ---- K6: out GEMM + bias + residual ----
__global__ __launch_bounds__(256) void k_out(const short* __restrict__ aoin,
                                             const short* __restrict__ wb,
                                             const float* __restrict__ ob,
                                             const float* __restrict__ x,
                                             float* __restrict__ out){
  __shared__ short As[128][40];
  __shared__ short Bs[128][40];
  int m0 = blockIdx.x << 7;
  int n0 = blockIdx.y << 7;
  int tid = threadIdx.x;
  int lane = tid & 63, wid = tid >> 6;
  int wm = (wid >> 1) << 6, wn = (wid & 1) << 6;
  int l15 = lane & 15, lg = lane >> 4;
  const f32x4 fz = {0.f,0.f,0.f,0.f};
  f32x4 acc[4][4];
  for (int i=0;i<4;i++) for(int j=0;j<4;j++) acc[i][j] = fz;
  for (int k0 = 0; k0 < NC; k0 += 32){
    __syncthreads();
    for (int it = 0; it < 2; ++it){
      int c = it*256 + tid;
      int r = c >> 2, kk8 = (c & 3) << 3;
      *(short8*)&As[r][kk8] = *(const short8*)&aoin[((size_t)(m0 + r))*NC + k0 + kk8];
      *(short8*)&Bs[r][kk8] = *(const short8*)&wb  [((size_t)(n0 + r))*NC + k0 + kk8];
    }
    __syncthreads();
    short8 a[4], b[4];
    for (int mf=0; mf<4; ++mf) a[mf] = *(const short8*)&As[wm + mf*16 + l15][lg*8];
    for (int nf=0; nf<4; ++nf) b[nf] = *(const short8*)&Bs[wn + nf*16 + l15][lg*8];
    for (int mf=0; mf<4; ++mf)
      for (int nf=0; nf<4; ++nf)
        acc[mf][nf] = __builtin_amdgcn_mfma_f32_16x16x32_bf16(a[mf], b[nf], acc[mf][nf], 0,0,0);
  }
  for (int mf=0; mf<4; ++mf)
    for (int nf=0; nf<4; ++nf)
      for (int r=0; r<4; ++r){
        int m = m0 + wm + mf*16 + lg*4 + r;
        int o = n0 + wn + nf*16 + l15;
        int b_ = m >> 12, s = m & 4095;
        size_t idx = ((size_t)b_*NC + o)*NS + s;
        out[idx] = acc[mf][nf][r] + ob[o] + x[idx];
      }
}

extern "C" void kernel_launch(void* const* d_in, const int* in_sizes, int n_in,
                              void* d_out, int out_size, void* d_ws, size_t ws_size,
                              hipStream_t stream){
  const float* x   = (const float*)d_in[0];
  const float* gnw = (const float*)d_in[1];
  const float* gnb = (const float*)d_in[2];
  const float* pw  = (const float*)d_in[3];
  const float* pb  = (const float*)d_in[4];
  const float* ow  = (const float*)d_in[5];
  const float* ob  = (const float*)d_in[6];
  float* out = (float*)d_out;

  char* ws = (char*)d_ws;
  float* mean = (float*)ws;
  float* rstd = mean + 64;
  short* wqkv = (short*)(ws + 512);
  short* wout = wqkv + NQKV*NC;
  short* h    = wout + NC*NC;
  short* qb   = h   + (size_t)NB*NS*NC;
  short* kb   = qb  + (size_t)NB*NH*NS*DK;
  short* vtb  = kb  + (size_t)NB*NH*NS*DK;
  short* ao   = vtb + (size_t)NB*NH*NS*DK;

  k_gnstats<<<64, 256, 0, stream>>>(x, mean, rstd);
  k_cvtw<<<768, 256, 0, stream>>>(pw, ow, wqkv, wout);
  k_gnapply<<<128, 256, 0, stream>>>(x, gnw, gnb, mean, rstd, h);
  k_qkv<<<dim3(64, 6), 256, 0, stream>>>(h, wqkv, pb, qb, kb, vtb);
  k_attn<<<256, 1024, sizeof(SMK), stream>>>(qb, kb, vtb, ao);
  k_out<<<dim3(64, 2), 256, 0, stream>>>(ao, wout, ob, x, out);
}

// Round 7
// 121.827 us; speedup vs baseline: 2.1394x; 1.0702x over previous
//
#include <hip/hip_runtime.h>
#include <math.h>

#define NB 2
#define NC 256
#define NS 4096
#define NG 32
#define CPG 8
#define NH 4
#define DK 64
#define NQKV 768
#define NKG 4      /* kv groups in k_attn */
#define TPG 16     /* tiles (of 64 kv) per group */
#define QS 0.18033688011112042f   /* 0.125 * log2(e): folds attn scale + exp->exp2 */

typedef __attribute__((ext_vector_type(8))) short short8;
typedef __attribute__((ext_vector_type(4))) float f32x4;
typedef __attribute__((ext_vector_type(16))) float f32x16;
typedef __attribute__((ext_vector_type(4))) unsigned uint4v;

union U8 { uint4v u; short8 s; };

__device__ __forceinline__ short f2bf(float f){
  union { float f; unsigned u; } v; v.f = f;
  unsigned r = v.u + 0x7fffu + ((v.u >> 16) & 1u);
  return (short)(r >> 16);
}
__device__ __forceinline__ float ex2(float x){          // hardware 2^x
  float y; asm("v_exp_f32 %0, %1" : "=v"(y) : "v"(x)); return y;
}
__device__ __forceinline__ unsigned cvtpk(float lo, float hi){ // bf16(lo)|bf16(hi)<<16, RNE
  unsigned u; asm("v_cvt_pk_bf16_f32 %0, %1, %2" : "=v"(u) : "v"(lo), "v"(hi)); return u;
}
// x' (lanes>=32) <- y[lane-32]; y' (lanes<32) <- x[lane+32]
__device__ __forceinline__ void pl32swap(unsigned &x, unsigned &y){
  asm("v_permlane32_swap_b32 %0, %1" : "+v"(x), "+v"(y));
}

// ---- K1: fused group-norm stats (blocks 0..63) + weight cvt (blocks 64..831) ----
__global__ __launch_bounds__(256) void k_prep(const float* __restrict__ x,
                                              const float* __restrict__ pw,
                                              const float* __restrict__ ow,
                                              float* __restrict__ mean,
                                              float* __restrict__ rstd,
                                              short* __restrict__ pwb,
                                              short* __restrict__ owb){
  int bk = blockIdx.x;
  if (bk < 64){
    const float* base = x + (size_t)bk * (CPG*NS);
    float s = 0.f, ss = 0.f;
    for (int i = threadIdx.x; i < CPG*NS; i += 256){
      float v = base[i]; s += v; ss += v*v;
    }
    for (int o = 32; o > 0; o >>= 1){ s += __shfl_down(s, o); ss += __shfl_down(ss, o); }
    __shared__ float red[8];
    int w = threadIdx.x >> 6;
    if ((threadIdx.x & 63) == 0){ red[w] = s; red[4+w] = ss; }
    __syncthreads();
    if (threadIdx.x == 0){
      float S  = red[0]+red[1]+red[2]+red[3];
      float SS = red[4]+red[5]+red[6]+red[7];
      const float inv = 1.f/(float)(CPG*NS);
      float m = S*inv; float var = SS*inv - m*m;
      mean[bk] = m; rstd[bk] = rsqrtf(var + 1e-5f);
    }
  } else {
    int i = (bk - 64)*256 + threadIdx.x;
    if (i < NQKV*NC) pwb[i] = f2bf(pw[i]);
    if (i < NC*NC)   owb[i] = f2bf(ow[i]);
  }
}

// ---- K2: normalize + transpose [B,C,S] -> h[B,S,C] bf16 (float4 reads, 16B writes) ----
__global__ __launch_bounds__(256) void k_gnapply(const float* __restrict__ x,
                                                 const float* __restrict__ gw,
                                                 const float* __restrict__ gb,
                                                 const float* __restrict__ mean,
                                                 const float* __restrict__ rstd,
                                                 short* __restrict__ h){
  __shared__ short tile[64][264];              // 264*2B = 16B-aligned rows, bank step 4
  int b  = blockIdx.x >> 6;
  int s0 = (blockIdx.x & 63) << 6;
  int tid = threadIdx.x;
  int sl4 = (tid & 15) << 2;                   // s offset 0,4,..,60
  int cb  = tid >> 4;                          // 0..15
  #pragma unroll 4
  for (int p = 0; p < 16; ++p){
    int c = p*16 + cb;
    int sg = (b << 5) + (c >> 3);
    float mu = mean[sg], rs = rstd[sg], w = gw[c], bb = gb[c];
    f32x4 v = *(const f32x4*)&x[((size_t)b*NC + c)*NS + s0 + sl4];
    tile[sl4+0][c] = f2bf((v[0]-mu)*rs*w + bb);
    tile[sl4+1][c] = f2bf((v[1]-mu)*rs*w + bb);
    tile[sl4+2][c] = f2bf((v[2]-mu)*rs*w + bb);
    tile[sl4+3][c] = f2bf((v[3]-mu)*rs*w + bb);
  }
  __syncthreads();
  #pragma unroll
  for (int it = 0; it < 8; ++it){
    int idx = it*256 + tid;
    int row = idx >> 5, ch = (idx & 31) << 3;
    uint4v pv = *(const uint4v*)&tile[row][ch];
    *(uint4v*)&h[((size_t)b*NS + s0 + row)*NC + ch] = pv;
  }
}

// ---- K4: QKV GEMM with scatter epilogue; q gets QS scale folded in ----
__global__ __launch_bounds__(256) void k_qkv(const short* __restrict__ h,
                                             const short* __restrict__ wb,
                                             const float* __restrict__ pb,
                                             short* __restrict__ qo,
                                             short* __restrict__ ko,
                                             short* __restrict__ vto){
  __shared__ short As[128][40];
  __shared__ short Bs[128][40];
  int m0 = blockIdx.x << 7;
  int n0 = blockIdx.y << 7;
  int tid = threadIdx.x;
  int lane = tid & 63, wid = tid >> 6;
  int wm = (wid >> 1) << 6, wn = (wid & 1) << 6;
  int l15 = lane & 15, lg = lane >> 4;
  const f32x4 fz = {0.f,0.f,0.f,0.f};
  f32x4 acc[4][4];
  for (int i=0;i<4;i++) for(int j=0;j<4;j++) acc[i][j] = fz;
  for (int k0 = 0; k0 < NC; k0 += 32){
    __syncthreads();
    for (int it = 0; it < 2; ++it){
      int c = it*256 + tid;
      int r = c >> 2, kk8 = (c & 3) << 3;
      *(short8*)&As[r][kk8] = *(const short8*)&h [((size_t)(m0 + r))*NC + k0 + kk8];
      *(short8*)&Bs[r][kk8] = *(const short8*)&wb[((size_t)(n0 + r))*NC + k0 + kk8];
    }
    __syncthreads();
    short8 a[4], b[4];
    for (int mf=0; mf<4; ++mf) a[mf] = *(const short8*)&As[wm + mf*16 + l15][lg*8];
    for (int nf=0; nf<4; ++nf) b[nf] = *(const short8*)&Bs[wn + nf*16 + l15][lg*8];
    for (int mf=0; mf<4; ++mf)
      for (int nf=0; nf<4; ++nf)
        acc[mf][nf] = __builtin_amdgcn_mfma_f32_16x16x32_bf16(a[mf], b[nf], acc[mf][nf], 0,0,0);
  }
  for (int mf=0; mf<4; ++mf)
    for (int nf=0; nf<4; ++nf)
      for (int r=0; r<4; ++r){
        int m = m0 + wm + mf*16 + lg*4 + r;
        int o = n0 + wn + nf*16 + l15;
        float val = acc[mf][nf][r] + pb[o];
        int b_ = m >> 12, s = m & 4095;
        int hh = o / 192, rem = o - hh*192;
        int t = rem >> 6, d = rem & 63;
        size_t bh = (size_t)(b_*NH + hh);
        if (t == 0)      qo [(bh*NS + s)*DK + d] = f2bf(val * QS);
        else if (t == 1) ko [(bh*NS + s)*DK + d] = f2bf(val);
        else             vto[(bh*DK + d)*NS + s] = f2bf(val);
      }
}

// ---- K5: flash attention, 32x32 MFMA, register-P, 16 waves (4 kv-groups x 4 q-subtiles),
//          double-buffered LDS (1 barrier/tile), defer-rescale, setprio, ZV-seeded acc ----
struct SMK { short kv[NKG][2][2][64][72]; };   // [group][buf][K/V][row][col+pad] = 147456 B
struct SMC {                                    // epilogue overlay (138240 B)
  float gOB[3][4][64][33];
  float ml[3][4][2][32];
  float fOB[4][64][33];
};

__global__ __launch_bounds__(1024, 4) void k_attn(const short* __restrict__ q,
                                                  const short* __restrict__ k,
                                                  const short* __restrict__ vt,
                                                  short* __restrict__ ao){
  extern __shared__ char smem[];
  SMK* sk = (SMK*)smem;
  SMC* sc = (SMC*)smem;

  int blk = blockIdx.x;
  int q0 = (blk & 31) << 7;          // 32 q-blocks of 128
  int bh = blk >> 5;
  const short* Qb = q  + (size_t)bh*NS*DK;
  const short* Kb = k  + (size_t)bh*NS*DK;
  const short* Vb = vt + (size_t)bh*DK*NS;
  int tid = threadIdx.x, lane = tid & 63, wid = tid >> 6;
  int l31 = lane & 31, hi = lane >> 5;
  int g = wid >> 2, wq = wid & 3;
  int gtid = tid & 255;
  int kvbase = g << 10;              // g*1024 kv rows

  // Q regs (B-frag): bq[s2] = Q[q = q0+wq*32+l31][d = s2*16 + hi*8 .. +7]
  short8 bq[4];
  {
    const short* qrow = Qb + (size_t)(q0 + wq*32 + l31)*DK + hi*8;
    #pragma unroll
    for (int s2 = 0; s2 < 4; ++s2) bq[s2] = *(const short8*)(qrow + s2*16);
  }

  f32x16 ZV;                          // persistent zero accumulator seed
  #pragma unroll
  for (int i = 0; i < 16; ++i) ZV[i] = 0.f;

  f32x16 ot0, ot1;                    // O^T acc: [d-half][reg]; col q = l31
  #pragma unroll
  for (int i = 0; i < 16; ++i){ ot0[i] = 0.f; ot1[i] = 0.f; }
  float mrun = -1e30f, lrun = 0.f;    // per-q (l31), log2 domain

  // hoisted staging bases: thread stages rows rA and rA+32 at 16B chunk colA
  int rA = gtid >> 3, colA = (gtid & 7) << 3;
  const short* KbA = Kb + (size_t)(kvbase + rA)*DK + colA;
  const short* VbA = Vb + (size_t)rA*NS + kvbase + colA;
  short* LK[2] = { &sk->kv[g][0][0][rA][colA], &sk->kv[g][1][0][rA][colA] };
  short* LV[2] = { &sk->kv[g][0][1][rA][colA], &sk->kv[g][1][1][rA][colA] };

  short8 kpre[2], vpre[2];
  kpre[0] = *(const short8*)(KbA);
  kpre[1] = *(const short8*)(KbA + 32*DK);
  vpre[0] = *(const short8*)(VbA);
  vpre[1] = *(const short8*)(VbA + (size_t)32*NS);
  *(short8*)(LK[0])         = kpre[0];
  *(short8*)(LK[0] + 32*72) = kpre[1];
  *(short8*)(LV[0])         = vpre[0];
  *(short8*)(LV[0] + 32*72) = vpre[1];
  kpre[0] = *(const short8*)(KbA + 64*DK);
  kpre[1] = *(const short8*)(KbA + 96*DK);
  vpre[0] = *(const short8*)(VbA + 64);
  vpre[1] = *(const short8*)(VbA + (size_t)32*NS + 64);

  for (int t = 0; t < TPG; ++t){
    __syncthreads();                 // buf[(t+1)&1] free (tile t-1 done) + buf[t&1] ready
    if (t + 1 < TPG){
      int nb = (t + 1) & 1;
      *(short8*)(LK[nb])         = kpre[0];
      *(short8*)(LK[nb] + 32*72) = kpre[1];
      *(short8*)(LV[nb])         = vpre[0];
      *(short8*)(LV[nb] + 32*72) = vpre[1];
    }
    if (t + 2 < TPG){
      const short* Kt = KbA + (size_t)(t + 2)*64*DK;
      const short* Vt = VbA + (t + 2)*64;
      kpre[0] = *(const short8*)(Kt);
      kpre[1] = *(const short8*)(Kt + 32*DK);
      vpre[0] = *(const short8*)(Vt);
      vpre[1] = *(const short8*)(Vt + (size_t)32*NS);
    }
    const short (*Kl)[72] = sk->kv[g][t & 1][0];
    const short (*Vl)[72] = sk->kv[g][t & 1][1];
    // S^T[kv][q] = K x Q (first MFMA seeded with ZV: no per-tile zero-init)
    const short* Kr0 = &Kl[l31][hi*8];
    const short* Kr1 = &Kl[32 + l31][hi*8];
    __builtin_amdgcn_s_setprio(1);
    f32x16 st0, st1;
    {
      short8 ka0 = *(const short8*)(Kr0);
      short8 ka1 = *(const short8*)(Kr1);
      st0 = __builtin_amdgcn_mfma_f32_32x32x16_bf16(ka0, bq[0], ZV, 0,0,0);
      st1 = __builtin_amdgcn_mfma_f32_32x32x16_bf16(ka1, bq[0], ZV, 0,0,0);
    }
    #pragma unroll
    for (int s2 = 1; s2 < 4; ++s2){
      short8 ka0 = *(const short8*)(Kr0 + s2*16);
      short8 ka1 = *(const short8*)(Kr1 + s2*16);
      st0 = __builtin_amdgcn_mfma_f32_32x32x16_bf16(ka0, bq[s2], st0, 0,0,0);
      st1 = __builtin_amdgcn_mfma_f32_32x32x16_bf16(ka1, bq[s2], st1, 0,0,0);
    }
    __builtin_amdgcn_s_setprio(0);
    // online softmax for q = l31 (lane^32 holds the other 32 kv rows)
    float mx = -1e30f;
    #pragma unroll
    for (int i = 0; i < 16; ++i) mx = fmaxf(mx, fmaxf(st0[i], st1[i]));
    mx = fmaxf(mx, __shfl_xor(mx, 32));
    if (!__all(mx - mrun <= 8.f)){   // defer-rescale: P bounded by 2^8, bf16-safe
      float mnew = fmaxf(mrun, mx);
      float corr = ex2(mrun - mnew);
      lrun *= corr;
      #pragma unroll
      for (int i = 0; i < 16; ++i){ ot0[i] *= corr; ot1[i] *= corr; }
      mrun = mnew;
    }
    float p0[16], p1[16]; float ps = 0.f;
    #pragma unroll
    for (int i = 0; i < 16; ++i){
      p0[i] = ex2(st0[i] - mrun); p1[i] = ex2(st1[i] - mrun);
      ps += p0[i] + p1[i];
    }
    ps += __shfl_xor(ps, 32);
    lrun += ps;
    // pack P -> PV B-frags via cvt_pk + permlane32_swap; PV: O^T += V^T x P
    unsigned pk0[8], pk1[8];
    #pragma unroll
    for (int a = 0; a < 4; ++a){
      pk0[a]     = cvtpk(p0[4*a+0], p0[4*a+1]);
      pk1[a]     = cvtpk(p0[4*a+2], p0[4*a+3]);
      pk0[4 + a] = cvtpk(p1[4*a+0], p1[4*a+1]);
      pk1[4 + a] = cvtpk(p1[4*a+2], p1[4*a+3]);
    }
    const short* Vr0 = &Vl[l31][hi*8];
    const short* Vr1 = &Vl[32 + l31][hi*8];
    __builtin_amdgcn_s_setprio(1);
    #pragma unroll
    for (int i2 = 0; i2 < 4; ++i2){
      unsigned w0 = pk0[2*i2], w2 = pk0[2*i2+1]; pl32swap(w0, w2);
      unsigned w1 = pk1[2*i2], w3 = pk1[2*i2+1]; pl32swap(w1, w3);
      U8 cv; cv.u = (uint4v){w0, w1, w2, w3};
      short8 av0 = *(const short8*)(Vr0 + i2*16);
      short8 av1 = *(const short8*)(Vr1 + i2*16);
      ot0 = __builtin_amdgcn_mfma_f32_32x32x16_bf16(av0, cv.s, ot0, 0,0,0);
      ot1 = __builtin_amdgcn_mfma_f32_32x32x16_bf16(av1, cv.s, ot1, 0,0,0);
    }
    __builtin_amdgcn_s_setprio(0);
  }

  // ---- 4-way merge through LDS overlay ----
  __syncthreads();
  if (g > 0){
    #pragma unroll
    for (int r2 = 0; r2 < 16; ++r2){
      int dl = (r2 & 3) + 8*(r2 >> 2) + 4*hi;
      sc->gOB[g-1][wq][dl][l31]      = ot0[r2];
      sc->gOB[g-1][wq][32 + dl][l31] = ot1[r2];
    }
    if (hi == 0){ sc->ml[g-1][wq][0][l31] = mrun; sc->ml[g-1][wq][1][l31] = lrun; }
  }
  __syncthreads();
  if (g == 0){
    float m1 = sc->ml[0][wq][0][l31], l1 = sc->ml[0][wq][1][l31];
    float m2 = sc->ml[1][wq][0][l31], l2 = sc->ml[1][wq][1][l31];
    float m3 = sc->ml[2][wq][0][l31], l3 = sc->ml[2][wq][1][l31];
    float M  = fmaxf(fmaxf(mrun, m1), fmaxf(m2, m3));
    float w0 = ex2(mrun - M), w1 = ex2(m1 - M), w2 = ex2(m2 - M), w3 = ex2(m3 - M);
    float inv = 1.f/(lrun*w0 + l1*w1 + l2*w2 + l3*w3);
    w0 *= inv; w1 *= inv; w2 *= inv; w3 *= inv;
    #pragma unroll
    for (int r2 = 0; r2 < 16; ++r2){
      int dl = (r2 & 3) + 8*(r2 >> 2) + 4*hi;
      sc->fOB[wq][dl][l31] = ot0[r2]*w0 + sc->gOB[0][wq][dl][l31]*w1
                           + sc->gOB[1][wq][dl][l31]*w2 + sc->gOB[2][wq][dl][l31]*w3;
      sc->fOB[wq][32+dl][l31] = ot1[r2]*w0 + sc->gOB[0][wq][32+dl][l31]*w1
                              + sc->gOB[1][wq][32+dl][l31]*w2 + sc->gOB[2][wq][32+dl][l31]*w3;
    }
  }
  __syncthreads();
  // coalesced writeout: 1024 threads, thread -> (q row, 8-d chunk)
  {
    int ql = tid >> 3, dc = (tid & 7) << 3;
    int b_ = bh >> 2, hh = bh & 3;
    float v2[8];
    #pragma unroll
    for (int i = 0; i < 8; ++i) v2[i] = sc->fOB[ql >> 5][dc + i][ql & 31];
    uint4v wa = { cvtpk(v2[0],v2[1]), cvtpk(v2[2],v2[3]),
                  cvtpk(v2[4],v2[5]), cvtpk(v2[6],v2[7]) };
    size_t base = ((size_t)b_*NS + q0 + ql)*NC + hh*DK + dc;
    *(uint4v*)&ao[base] = wa;
  }
}

// ---- K6: out GEMM + bias + residual, BM=64 -> 256 blocks ----
__global__ __launch_bounds__(256) void k_out(const short* __restrict__ aoin,
                                             const short* __restrict__ wb,
                                             const float* __restrict__ ob,
                                             const float* __restrict__ x,
                                             float* __restrict__ out){
  __shared__ short As[64][40];
  __shared__ short Bs[128][40];
  int m0 = blockIdx.x << 6;
  int n0 = blockIdx.y << 7;
  int tid = threadIdx.x;
  int lane = tid & 63, wid = tid >> 6;
  int wm = (wid >> 1) << 5, wn = (wid & 1) << 6;
  int l15 = lane & 15, lg = lane >> 4;
  const f32x4 fz = {0.f,0.f,0.f,0.f};
  f32x4 acc[2][4];
  for (int i=0;i<2;i++) for(int j=0;j<4;j++) acc[i][j] = fz;
  for (int k0 = 0; k0 < NC; k0 += 32){
    __syncthreads();
    {
      int c = tid;
      int r = c >> 2, kk8 = (c & 3) << 3;
      *(short8*)&As[r][kk8] = *(const short8*)&aoin[((size_t)(m0 + r))*NC + k0 + kk8];
    }
    for (int it = 0; it < 2; ++it){
      int c = it*256 + tid;
      int r = c >> 2, kk8 = (c & 3) << 3;
      *(short8*)&Bs[r][kk8] = *(const short8*)&wb[((size_t)(n0 + r))*NC + k0 + kk8];
    }
    __syncthreads();
    short8 a[2], b[4];
    for (int mf=0; mf<2; ++mf) a[mf] = *(const short8*)&As[wm + mf*16 + l15][lg*8];
    for (int nf=0; nf<4; ++nf) b[nf] = *(const short8*)&Bs[wn + nf*16 + l15][lg*8];
    for (int mf=0; mf<2; ++mf)
      for (int nf=0; nf<4; ++nf)
        acc[mf][nf] = __builtin_amdgcn_mfma_f32_16x16x32_bf16(a[mf], b[nf], acc[mf][nf], 0,0,0);
  }
  for (int mf=0; mf<2; ++mf)
    for (int nf=0; nf<4; ++nf)
      for (int r=0; r<4; ++r){
        int m = m0 + wm + mf*16 + lg*4 + r;
        int o = n0 + wn + nf*16 + l15;
        int b_ = m >> 12, s = m & 4095;
        size_t idx = ((size_t)b_*NC + o)*NS + s;
        out[idx] = acc[mf][nf][r] + ob[o] + x[idx];
      }
}

extern "C" void kernel_launch(void* const* d_in, const int* in_sizes, int n_in,
                              void* d_out, int out_size, void* d_ws, size_t ws_size,
                              hipStream_t stream){
  const float* x   = (const float*)d_in[0];
  const float* gnw = (const float*)d_in[1];
  const float* gnb = (const float*)d_in[2];
  const float* pw  = (const float*)d_in[3];
  const float* pb  = (const float*)d_in[4];
  const float* ow  = (const float*)d_in[5];
  const float* ob  = (const float*)d_in[6];
  float* out = (float*)d_out;

  char* ws = (char*)d_ws;
  float* mean = (float*)ws;
  float* rstd = mean + 64;
  short* wqkv = (short*)(ws + 512);
  short* wout = wqkv + NQKV*NC;
  short* h    = wout + NC*NC;
  short* qb   = h   + (size_t)NB*NS*NC;
  short* kb   = qb  + (size_t)NB*NH*NS*DK;
  short* vtb  = kb  + (size_t)NB*NH*NS*DK;
  short* ao   = vtb + (size_t)NB*NH*NS*DK;

  k_prep<<<832, 256, 0, stream>>>(x, pw, ow, mean, rstd, wqkv, wout);
  k_gnapply<<<128, 256, 0, stream>>>(x, gnw, gnb, mean, rstd, h);
  k_qkv<<<dim3(64, 6), 256, 0, stream>>>(h, wqkv, pb, qb, kb, vtb);
  k_attn<<<256, 1024, sizeof(SMK), stream>>>(qb, kb, vtb, ao);
  k_out<<<dim3(128, 2), 256, 0, stream>>>(ao, wout, ob, x, out);
}

// Round 8
// 115.019 us; speedup vs baseline: 2.2661x; 1.0592x over previous
//
#include <hip/hip_runtime.h>
#include <math.h>

#define NB 2
#define NC 256
#define NS 4096
#define NG 32
#define CPG 8
#define NH 4
#define DK 64
#define NQKV 768
#define NKG 4      /* kv groups in k_attn */
#define TPG 16     /* tiles (of 64 kv) per group */
#define QS 0.18033688011112042f   /* 0.125 * log2(e): folds attn scale + exp->exp2 */

typedef __attribute__((ext_vector_type(8))) short short8;
typedef __attribute__((ext_vector_type(4))) float f32x4;
typedef __attribute__((ext_vector_type(16))) float f32x16;
typedef __attribute__((ext_vector_type(4))) unsigned uint4v;

union U8 { uint4v u; short8 s; };

__device__ __forceinline__ short f2bf(float f){
  union { float f; unsigned u; } v; v.f = f;
  unsigned r = v.u + 0x7fffu + ((v.u >> 16) & 1u);
  return (short)(r >> 16);
}
__device__ __forceinline__ float ex2(float x){          // hardware 2^x
  float y; asm("v_exp_f32 %0, %1" : "=v"(y) : "v"(x)); return y;
}
__device__ __forceinline__ unsigned cvtpk(float lo, float hi){ // bf16(lo)|bf16(hi)<<16, RNE
  unsigned u; asm("v_cvt_pk_bf16_f32 %0, %1, %2" : "=v"(u) : "v"(lo), "v"(hi)); return u;
}
// x' (lanes>=32) <- y[lane-32]; y' (lanes<32) <- x[lane+32]
__device__ __forceinline__ void pl32swap(unsigned &x, unsigned &y){
  asm("v_permlane32_swap_b32 %0, %1" : "+v"(x), "+v"(y));
}

// ---- K1: fused group-norm stats (blocks 0..63) + weight cvt (blocks 64..831) ----
__global__ __launch_bounds__(256) void k_prep(const float* __restrict__ x,
                                              const float* __restrict__ pw,
                                              const float* __restrict__ ow,
                                              float* __restrict__ mean,
                                              float* __restrict__ rstd,
                                              short* __restrict__ pwb,
                                              short* __restrict__ owb){
  int bk = blockIdx.x;
  if (bk < 64){
    const float* base = x + (size_t)bk * (CPG*NS);
    float s = 0.f, ss = 0.f;
    for (int i = threadIdx.x; i < CPG*NS; i += 256){
      float v = base[i]; s += v; ss += v*v;
    }
    for (int o = 32; o > 0; o >>= 1){ s += __shfl_down(s, o); ss += __shfl_down(ss, o); }
    __shared__ float red[8];
    int w = threadIdx.x >> 6;
    if ((threadIdx.x & 63) == 0){ red[w] = s; red[4+w] = ss; }
    __syncthreads();
    if (threadIdx.x == 0){
      float S  = red[0]+red[1]+red[2]+red[3];
      float SS = red[4]+red[5]+red[6]+red[7];
      const float inv = 1.f/(float)(CPG*NS);
      float m = S*inv; float var = SS*inv - m*m;
      mean[bk] = m; rstd[bk] = rsqrtf(var + 1e-5f);
    }
  } else {
    int i = (bk - 64)*256 + threadIdx.x;
    if (i < NQKV*NC) pwb[i] = f2bf(pw[i]);
    if (i < NC*NC)   owb[i] = f2bf(ow[i]);
  }
}

// ---- K2: normalize + transpose [B,C,S] -> h[B,S,C] bf16 (float4 reads, 16B writes) ----
__global__ __launch_bounds__(256) void k_gnapply(const float* __restrict__ x,
                                                 const float* __restrict__ gw,
                                                 const float* __restrict__ gb,
                                                 const float* __restrict__ mean,
                                                 const float* __restrict__ rstd,
                                                 short* __restrict__ h){
  __shared__ short tile[64][264];              // 264*2B = 16B-aligned rows, bank step 4
  int b  = blockIdx.x >> 6;
  int s0 = (blockIdx.x & 63) << 6;
  int tid = threadIdx.x;
  int sl4 = (tid & 15) << 2;                   // s offset 0,4,..,60
  int cb  = tid >> 4;                          // 0..15
  #pragma unroll 4
  for (int p = 0; p < 16; ++p){
    int c = p*16 + cb;
    int sg = (b << 5) + (c >> 3);
    float mu = mean[sg], rs = rstd[sg], w = gw[c], bb = gb[c];
    f32x4 v = *(const f32x4*)&x[((size_t)b*NC + c)*NS + s0 + sl4];
    tile[sl4+0][c] = f2bf((v[0]-mu)*rs*w + bb);
    tile[sl4+1][c] = f2bf((v[1]-mu)*rs*w + bb);
    tile[sl4+2][c] = f2bf((v[2]-mu)*rs*w + bb);
    tile[sl4+3][c] = f2bf((v[3]-mu)*rs*w + bb);
  }
  __syncthreads();
  #pragma unroll
  for (int it = 0; it < 8; ++it){
    int idx = it*256 + tid;
    int row = idx >> 5, ch = (idx & 31) << 3;
    uint4v pv = *(const uint4v*)&tile[row][ch];
    *(uint4v*)&h[((size_t)b*NS + s0 + row)*NC + ch] = pv;
  }
}

// ---- K4: QKV GEMM, BK=64 (4 K-iters), scatter epilogue; q gets QS scale folded in ----
__global__ __launch_bounds__(256) void k_qkv(const short* __restrict__ h,
                                             const short* __restrict__ wb,
                                             const float* __restrict__ pb,
                                             short* __restrict__ qo,
                                             short* __restrict__ ko,
                                             short* __restrict__ vto){
  __shared__ short As[128][72];
  __shared__ short Bs[128][72];
  int m0 = blockIdx.x << 7;
  int n0 = blockIdx.y << 7;
  int tid = threadIdx.x;
  int lane = tid & 63, wid = tid >> 6;
  int wm = (wid >> 1) << 6, wn = (wid & 1) << 6;
  int l15 = lane & 15, lg = lane >> 4;
  const f32x4 fz = {0.f,0.f,0.f,0.f};
  f32x4 acc[4][4];
  for (int i=0;i<4;i++) for(int j=0;j<4;j++) acc[i][j] = fz;
  for (int k0 = 0; k0 < NC; k0 += 64){
    __syncthreads();
    for (int it = 0; it < 4; ++it){
      int c = it*256 + tid;
      int r = c >> 3, ch = (c & 7) << 3;
      *(short8*)&As[r][ch] = *(const short8*)&h [((size_t)(m0 + r))*NC + k0 + ch];
      *(short8*)&Bs[r][ch] = *(const short8*)&wb[((size_t)(n0 + r))*NC + k0 + ch];
    }
    __syncthreads();
    #pragma unroll
    for (int kk = 0; kk < 2; ++kk){
      short8 a[4], b[4];
      for (int mf=0; mf<4; ++mf) a[mf] = *(const short8*)&As[wm + mf*16 + l15][kk*32 + lg*8];
      for (int nf=0; nf<4; ++nf) b[nf] = *(const short8*)&Bs[wn + nf*16 + l15][kk*32 + lg*8];
      for (int mf=0; mf<4; ++mf)
        for (int nf=0; nf<4; ++nf)
          acc[mf][nf] = __builtin_amdgcn_mfma_f32_16x16x32_bf16(a[mf], b[nf], acc[mf][nf], 0,0,0);
    }
  }
  for (int mf=0; mf<4; ++mf)
    for (int nf=0; nf<4; ++nf)
      for (int r=0; r<4; ++r){
        int m = m0 + wm + mf*16 + lg*4 + r;
        int o = n0 + wn + nf*16 + l15;
        float val = acc[mf][nf][r] + pb[o];
        int b_ = m >> 12, s = m & 4095;
        int hh = o / 192, rem = o - hh*192;
        int t = rem >> 6, d = rem & 63;
        size_t bh = (size_t)(b_*NH + hh);
        if (t == 0)      qo [(bh*NS + s)*DK + d] = f2bf(val * QS);
        else if (t == 1) ko [(bh*NS + s)*DK + d] = f2bf(val);
        else             vto[(bh*DK + d)*NS + s] = f2bf(val);
      }
}

// ---- K5: flash attention (R6 version, reverted): 32x32 MFMA, register-P, 16 waves,
//          double-buffered LDS (1 barrier/tile), defer-rescale ----
struct SMK { short kv[NKG][2][2][64][72]; };   // [group][buf][K/V][row][col+pad] = 147456 B
struct SMC {                                    // epilogue overlay (138240 B)
  float gOB[3][4][64][33];
  float ml[3][4][2][32];
  float fOB[4][64][33];
};

__global__ __launch_bounds__(1024, 4) void k_attn(const short* __restrict__ q,
                                                  const short* __restrict__ k,
                                                  const short* __restrict__ vt,
                                                  short* __restrict__ ao){
  extern __shared__ char smem[];
  SMK* sk = (SMK*)smem;
  SMC* sc = (SMC*)smem;

  int blk = blockIdx.x;
  int q0 = (blk & 31) << 7;          // 32 q-blocks of 128
  int bh = blk >> 5;
  const short* Qb = q  + (size_t)bh*NS*DK;
  const short* Kb = k  + (size_t)bh*NS*DK;
  const short* Vb = vt + (size_t)bh*DK*NS;
  int tid = threadIdx.x, lane = tid & 63, wid = tid >> 6;
  int l31 = lane & 31, hi = lane >> 5;
  int g = wid >> 2, wq = wid & 3;
  int gtid = tid & 255;
  int kvbase = g << 10;              // g*1024 kv rows

  // Q regs (B-frag): bq[s2] = Q[q = q0+wq*32+l31][d = s2*16 + hi*8 .. +7]
  short8 bq[4];
  {
    const short* qrow = Qb + (size_t)(q0 + wq*32 + l31)*DK + hi*8;
    #pragma unroll
    for (int s2 = 0; s2 < 4; ++s2) bq[s2] = *(const short8*)(qrow + s2*16);
  }

  f32x16 ot0, ot1;                    // O^T acc: [d-half][reg]; col q = l31
  #pragma unroll
  for (int i = 0; i < 16; ++i){ ot0[i] = 0.f; ot1[i] = 0.f; }
  float mrun = -1e30f, lrun = 0.f;    // per-q (l31), log2 domain

  // staging coords: c = it*256 + gtid -> row r, col (16B chunk)
  short8 kpre[2], vpre[2];
  #pragma unroll
  for (int it = 0; it < 2; ++it){    // tile 0 -> regs
    int c = it*256 + gtid, r = c >> 3, col = (c & 7) << 3;
    kpre[it] = *(const short8*)&Kb[(size_t)(kvbase + r)*DK + col];
    vpre[it] = *(const short8*)&Vb[(size_t)r*NS + kvbase + col];
  }
  #pragma unroll
  for (int it = 0; it < 2; ++it){    // tile 0 -> buf0 (no barrier yet; synced at loop top)
    int c = it*256 + gtid, r = c >> 3, col = (c & 7) << 3;
    *(short8*)&sk->kv[g][0][0][r][col] = kpre[it];
    *(short8*)&sk->kv[g][0][1][r][col] = vpre[it];
  }
  #pragma unroll
  for (int it = 0; it < 2; ++it){    // tile 1 -> regs
    int c = it*256 + gtid, r = c >> 3, col = (c & 7) << 3;
    kpre[it] = *(const short8*)&Kb[(size_t)(kvbase + 64 + r)*DK + col];
    vpre[it] = *(const short8*)&Vb[(size_t)r*NS + kvbase + 64 + col];
  }

  for (int t = 0; t < TPG; ++t){
    __syncthreads();                 // buf[(t+1)&1] free (tile t-1 done) + buf[t&1] ready
    if (t + 1 < TPG){
      int nb = (t + 1) & 1;
      #pragma unroll
      for (int it = 0; it < 2; ++it){
        int c = it*256 + gtid, r = c >> 3, col = (c & 7) << 3;
        *(short8*)&sk->kv[g][nb][0][r][col] = kpre[it];
        *(short8*)&sk->kv[g][nb][1][r][col] = vpre[it];
      }
    }
    if (t + 2 < TPG){
      int kv0 = kvbase + (t + 2)*64;
      #pragma unroll
      for (int it = 0; it < 2; ++it){
        int c = it*256 + gtid, r = c >> 3, col = (c & 7) << 3;
        kpre[it] = *(const short8*)&Kb[(size_t)(kv0 + r)*DK + col];
        vpre[it] = *(const short8*)&Vb[(size_t)r*NS + kv0 + col];
      }
    }
    const short (*Kl)[72] = sk->kv[g][t & 1][0];
    const short (*Vl)[72] = sk->kv[g][t & 1][1];
    // S^T[kv][q] = K x Q
    f32x16 st0, st1;
    #pragma unroll
    for (int i = 0; i < 16; ++i){ st0[i] = 0.f; st1[i] = 0.f; }
    const short* Kr0 = &Kl[l31][hi*8];
    const short* Kr1 = &Kl[32 + l31][hi*8];
    #pragma unroll
    for (int s2 = 0; s2 < 4; ++s2){
      short8 ka0 = *(const short8*)(Kr0 + s2*16);
      short8 ka1 = *(const short8*)(Kr1 + s2*16);
      st0 = __builtin_amdgcn_mfma_f32_32x32x16_bf16(ka0, bq[s2], st0, 0,0,0);
      st1 = __builtin_amdgcn_mfma_f32_32x32x16_bf16(ka1, bq[s2], st1, 0,0,0);
    }
    // online softmax for q = l31 (lane^32 holds the other 32 kv rows)
    float mx = -1e30f;
    #pragma unroll
    for (int i = 0; i < 16; ++i) mx = fmaxf(mx, fmaxf(st0[i], st1[i]));
    mx = fmaxf(mx, __shfl_xor(mx, 32));
    if (!__all(mx - mrun <= 8.f)){   // defer-rescale: P bounded by 2^8, bf16-safe
      float mnew = fmaxf(mrun, mx);
      float corr = ex2(mrun - mnew);
      lrun *= corr;
      #pragma unroll
      for (int i = 0; i < 16; ++i){ ot0[i] *= corr; ot1[i] *= corr; }
      mrun = mnew;
    }
    float p0[16], p1[16]; float ps = 0.f;
    #pragma unroll
    for (int i = 0; i < 16; ++i){
      p0[i] = ex2(st0[i] - mrun); p1[i] = ex2(st1[i] - mrun);
      ps += p0[i] + p1[i];
    }
    ps += __shfl_xor(ps, 32);
    lrun += ps;
    // pack P -> PV B-frags via cvt_pk + permlane32_swap; PV: O^T += V^T x P
    unsigned pk0[8], pk1[8];
    #pragma unroll
    for (int a = 0; a < 4; ++a){
      pk0[a]     = cvtpk(p0[4*a+0], p0[4*a+1]);
      pk1[a]     = cvtpk(p0[4*a+2], p0[4*a+3]);
      pk0[4 + a] = cvtpk(p1[4*a+0], p1[4*a+1]);
      pk1[4 + a] = cvtpk(p1[4*a+2], p1[4*a+3]);
    }
    const short* Vr0 = &Vl[l31][hi*8];
    const short* Vr1 = &Vl[32 + l31][hi*8];
    #pragma unroll
    for (int i2 = 0; i2 < 4; ++i2){
      unsigned w0 = pk0[2*i2], w2 = pk0[2*i2+1]; pl32swap(w0, w2);
      unsigned w1 = pk1[2*i2], w3 = pk1[2*i2+1]; pl32swap(w1, w3);
      U8 cv; cv.u = (uint4v){w0, w1, w2, w3};
      short8 av0 = *(const short8*)(Vr0 + i2*16);
      short8 av1 = *(const short8*)(Vr1 + i2*16);
      ot0 = __builtin_amdgcn_mfma_f32_32x32x16_bf16(av0, cv.s, ot0, 0,0,0);
      ot1 = __builtin_amdgcn_mfma_f32_32x32x16_bf16(av1, cv.s, ot1, 0,0,0);
    }
  }

  // ---- 4-way merge through LDS overlay ----
  __syncthreads();
  if (g > 0){
    #pragma unroll
    for (int r2 = 0; r2 < 16; ++r2){
      int dl = (r2 & 3) + 8*(r2 >> 2) + 4*hi;
      sc->gOB[g-1][wq][dl][l31]      = ot0[r2];
      sc->gOB[g-1][wq][32 + dl][l31] = ot1[r2];
    }
    if (hi == 0){ sc->ml[g-1][wq][0][l31] = mrun; sc->ml[g-1][wq][1][l31] = lrun; }
  }
  __syncthreads();
  if (g == 0){
    float m1 = sc->ml[0][wq][0][l31], l1 = sc->ml[0][wq][1][l31];
    float m2 = sc->ml[1][wq][0][l31], l2 = sc->ml[1][wq][1][l31];
    float m3 = sc->ml[2][wq][0][l31], l3 = sc->ml[2][wq][1][l31];
    float M  = fmaxf(fmaxf(mrun, m1), fmaxf(m2, m3));
    float w0 = ex2(mrun - M), w1 = ex2(m1 - M), w2 = ex2(m2 - M), w3 = ex2(m3 - M);
    float inv = 1.f/(lrun*w0 + l1*w1 + l2*w2 + l3*w3);
    w0 *= inv; w1 *= inv; w2 *= inv; w3 *= inv;
    #pragma unroll
    for (int r2 = 0; r2 < 16; ++r2){
      int dl = (r2 & 3) + 8*(r2 >> 2) + 4*hi;
      sc->fOB[wq][dl][l31] = ot0[r2]*w0 + sc->gOB[0][wq][dl][l31]*w1
                           + sc->gOB[1][wq][dl][l31]*w2 + sc->gOB[2][wq][dl][l31]*w3;
      sc->fOB[wq][32+dl][l31] = ot1[r2]*w0 + sc->gOB[0][wq][32+dl][l31]*w1
                              + sc->gOB[1][wq][32+dl][l31]*w2 + sc->gOB[2][wq][32+dl][l31]*w3;
    }
  }
  __syncthreads();
  // coalesced writeout: 1024 threads, thread -> (q row, 8-d chunk)
  {
    int ql = tid >> 3, dc = (tid & 7) << 3;
    int b_ = bh >> 2, hh = bh & 3;
    float v2[8];
    #pragma unroll
    for (int i = 0; i < 8; ++i) v2[i] = sc->fOB[ql >> 5][dc + i][ql & 31];
    uint4v wa = { cvtpk(v2[0],v2[1]), cvtpk(v2[2],v2[3]),
                  cvtpk(v2[4],v2[5]), cvtpk(v2[6],v2[7]) };
    size_t base = ((size_t)b_*NS + q0 + ql)*NC + hh*DK + dc;
    *(uint4v*)&ao[base] = wa;
  }
}

// ---- K6: out GEMM + bias + residual, BM=64 -> 256 blocks ----
__global__ __launch_bounds__(256) void k_out(const short* __restrict__ aoin,
                                             const short* __restrict__ wb,
                                             const float* __restrict__ ob,
                                             const float* __restrict__ x,
                                             float* __restrict__ out){
  __shared__ short As[64][40];
  __shared__ short Bs[128][40];
  int m0 = blockIdx.x << 6;
  int n0 = blockIdx.y << 7;
  int tid = threadIdx.x;
  int lane = tid & 63, wid = tid >> 6;
  int wm = (wid >> 1) << 5, wn = (wid & 1) << 6;
  int l15 = lane & 15, lg = lane >> 4;
  const f32x4 fz = {0.f,0.f,0.f,0.f};
  f32x4 acc[2][4];
  for (int i=0;i<2;i++) for(int j=0;j<4;j++) acc[i][j] = fz;
  for (int k0 = 0; k0 < NC; k0 += 32){
    __syncthreads();
    {
      int c = tid;
      int r = c >> 2, kk8 = (c & 3) << 3;
      *(short8*)&As[r][kk8] = *(const short8*)&aoin[((size_t)(m0 + r))*NC + k0 + kk8];
    }
    for (int it = 0; it < 2; ++it){
      int c = it*256 + tid;
      int r = c >> 2, kk8 = (c & 3) << 3;
      *(short8*)&Bs[r][kk8] = *(const short8*)&wb[((size_t)(n0 + r))*NC + k0 + kk8];
    }
    __syncthreads();
    short8 a[2], b[4];
    for (int mf=0; mf<2; ++mf) a[mf] = *(const short8*)&As[wm + mf*16 + l15][lg*8];
    for (int nf=0; nf<4; ++nf) b[nf] = *(const short8*)&Bs[wn + nf*16 + l15][lg*8];
    for (int mf=0; mf<2; ++mf)
      for (int nf=0; nf<4; ++nf)
        acc[mf][nf] = __builtin_amdgcn_mfma_f32_16x16x32_bf16(a[mf], b[nf], acc[mf][nf], 0,0,0);
  }
  for (int mf=0; mf<2; ++mf)
    for (int nf=0; nf<4; ++nf)
      for (int r=0; r<4; ++r){
        int m = m0 + wm + mf*16 + lg*4 + r;
        int o = n0 + wn + nf*16 + l15;
        int b_ = m >> 12, s = m & 4095;
        size_t idx = ((size_t)b_*NC + o)*NS + s;
        out[idx] = acc[mf][nf][r] + ob[o] + x[idx];
      }
}

extern "C" void kernel_launch(void* const* d_in, const int* in_sizes, int n_in,
                              void* d_out, int out_size, void* d_ws, size_t ws_size,
                              hipStream_t stream){
  const float* x   = (const float*)d_in[0];
  const float* gnw = (const float*)d_in[1];
  const float* gnb = (const float*)d_in[2];
  const float* pw  = (const float*)d_in[3];
  const float* pb  = (const float*)d_in[4];
  const float* ow  = (const float*)d_in[5];
  const float* ob  = (const float*)d_in[6];
  float* out = (float*)d_out;

  char* ws = (char*)d_ws;
  float* mean = (float*)ws;
  float* rstd = mean + 64;
  short* wqkv = (short*)(ws + 512);
  short* wout = wqkv + NQKV*NC;
  short* h    = wout + NC*NC;
  short* qb   = h   + (size_t)NB*NS*NC;
  short* kb   = qb  + (size_t)NB*NH*NS*DK;
  short* vtb  = kb  + (size_t)NB*NH*NS*DK;
  short* ao   = vtb + (size_t)NB*NH*NS*DK;

  k_prep<<<832, 256, 0, stream>>>(x, pw, ow, mean, rstd, wqkv, wout);
  k_gnapply<<<128, 256, 0, stream>>>(x, gnw, gnb, mean, rstd, h);
  k_qkv<<<dim3(64, 6), 256, 0, stream>>>(h, wqkv, pb, qb, kb, vtb);
  k_attn<<<256, 1024, sizeof(SMK), stream>>>(qb, kb, vtb, ao);
  k_out<<<dim3(128, 2), 256, 0, stream>>>(ao, wout, ob, x, out);
}

// Round 9
// 99.407 us; speedup vs baseline: 2.6220x; 1.1570x over previous
//
#include <hip/hip_runtime.h>
#include <math.h>

#define NB 2
#define NC 256
#define NS 4096
#define NG 32
#define CPG 8
#define NH 4
#define DK 64
#define NQKV 768
#define NKG 4      /* kv groups in k_attn */
#define TPG 16     /* tiles (of 64 kv) per group */
#define QS 0.18033688011112042f   /* 0.125 * log2(e): folds attn scale + exp->exp2 */

typedef __attribute__((ext_vector_type(8))) short short8;
typedef __attribute__((ext_vector_type(4))) float f32x4;
typedef __attribute__((ext_vector_type(16))) float f32x16;
typedef __attribute__((ext_vector_type(4))) unsigned uint4v;

union U8 { uint4v u; short8 s; };

__device__ __forceinline__ short f2bf(float f){
  union { float f; unsigned u; } v; v.f = f;
  unsigned r = v.u + 0x7fffu + ((v.u >> 16) & 1u);
  return (short)(r >> 16);
}
__device__ __forceinline__ float ex2(float x){          // hardware 2^x
  float y; asm("v_exp_f32 %0, %1" : "=v"(y) : "v"(x)); return y;
}
__device__ __forceinline__ unsigned cvtpk(float lo, float hi){ // bf16(lo)|bf16(hi)<<16, RNE
  unsigned u; asm("v_cvt_pk_bf16_f32 %0, %1, %2" : "=v"(u) : "v"(lo), "v"(hi)); return u;
}
// x' (lanes>=32) <- y[lane-32]; y' (lanes<32) <- x[lane+32]
__device__ __forceinline__ void pl32swap(unsigned &x, unsigned &y){
  asm("v_permlane32_swap_b32 %0, %1" : "+v"(x), "+v"(y));
}

// ---- K1: fused group-norm (stats + apply + transpose-write of h) and weight cvt ----
// blocks 0..63: one (b,group); slice is contiguous 8x4096 f32. Stats vectorized f32x4;
// then the SAME block normalizes its slice (L2-hot) and writes h[b,s,c] bf16.
__global__ __launch_bounds__(256) void k_prep(const float* __restrict__ x,
                                              const float* __restrict__ pw,
                                              const float* __restrict__ ow,
                                              const float* __restrict__ gw,
                                              const float* __restrict__ gb,
                                              short* __restrict__ h,
                                              short* __restrict__ pwb,
                                              short* __restrict__ owb){
  int bk = blockIdx.x;
  int tid = threadIdx.x;
  if (bk < 64){
    int b = bk >> 5, g = bk & 31;
    const float* base = x + (size_t)bk*(CPG*NS);
    const f32x4* b4 = (const f32x4*)base;
    float s = 0.f, ss = 0.f;
    for (int i = tid; i < (CPG*NS)/4; i += 256){
      f32x4 v = b4[i];
      s  += (v[0]+v[1])+(v[2]+v[3]);
      ss += (v[0]*v[0]+v[1]*v[1])+(v[2]*v[2]+v[3]*v[3]);
    }
    for (int o = 32; o > 0; o >>= 1){ s += __shfl_down(s,o); ss += __shfl_down(ss,o); }
    __shared__ float red[8];
    __shared__ float mrs[2];
    int w = tid >> 6;
    if ((tid & 63) == 0){ red[w] = s; red[4+w] = ss; }
    __syncthreads();
    if (tid == 0){
      float S  = red[0]+red[1]+red[2]+red[3];
      float SS = red[4]+red[5]+red[6]+red[7];
      const float inv = 1.f/(float)(CPG*NS);
      float m = S*inv; float var = SS*inv - m*m;
      mrs[0] = m; mrs[1] = rsqrtf(var + 1e-5f);
    }
    __syncthreads();
    float mu = mrs[0], rs = mrs[1];
    float wv[8], bv[8];
    #pragma unroll
    for (int c = 0; c < 8; ++c){
      wv[c] = gw[g*8 + c] * rs;
      bv[c] = gb[g*8 + c] - mu * wv[c];
    }
    short* hb = h + (size_t)b*NS*NC + g*8;
    for (int i = tid; i < NS; i += 256){   // thread -> s; reads coalesced per c
      unsigned u[4];
      #pragma unroll
      for (int c2 = 0; c2 < 4; ++c2){
        float v0 = base[(size_t)(2*c2  )*NS + i]*wv[2*c2  ] + bv[2*c2  ];
        float v1 = base[(size_t)(2*c2+1)*NS + i]*wv[2*c2+1] + bv[2*c2+1];
        u[c2] = cvtpk(v0, v1);
      }
      *(uint4v*)&hb[(size_t)i*NC] = (uint4v){u[0],u[1],u[2],u[3]};
    }
  } else {
    int i = (bk - 64)*256 + tid;
    if (i < NQKV*NC) pwb[i] = f2bf(pw[i]);
    if (i < NC*NC)   owb[i] = f2bf(ow[i]);
  }
}

// ---- K4: QKV GEMM, BK=64 (4 K-iters), scatter epilogue; q gets QS scale folded in ----
__global__ __launch_bounds__(256) void k_qkv(const short* __restrict__ h,
                                             const short* __restrict__ wb,
                                             const float* __restrict__ pb,
                                             short* __restrict__ qo,
                                             short* __restrict__ ko,
                                             short* __restrict__ vto){
  __shared__ short As[128][72];
  __shared__ short Bs[128][72];
  int m0 = blockIdx.x << 7;
  int n0 = blockIdx.y << 7;
  int tid = threadIdx.x;
  int lane = tid & 63, wid = tid >> 6;
  int wm = (wid >> 1) << 6, wn = (wid & 1) << 6;
  int l15 = lane & 15, lg = lane >> 4;
  const f32x4 fz = {0.f,0.f,0.f,0.f};
  f32x4 acc[4][4];
  for (int i=0;i<4;i++) for(int j=0;j<4;j++) acc[i][j] = fz;
  for (int k0 = 0; k0 < NC; k0 += 64){
    __syncthreads();
    for (int it = 0; it < 4; ++it){
      int c = it*256 + tid;
      int r = c >> 3, ch = (c & 7) << 3;
      *(short8*)&As[r][ch] = *(const short8*)&h [((size_t)(m0 + r))*NC + k0 + ch];
      *(short8*)&Bs[r][ch] = *(const short8*)&wb[((size_t)(n0 + r))*NC + k0 + ch];
    }
    __syncthreads();
    #pragma unroll
    for (int kk = 0; kk < 2; ++kk){
      short8 a[4], b[4];
      for (int mf=0; mf<4; ++mf) a[mf] = *(const short8*)&As[wm + mf*16 + l15][kk*32 + lg*8];
      for (int nf=0; nf<4; ++nf) b[nf] = *(const short8*)&Bs[wn + nf*16 + l15][kk*32 + lg*8];
      for (int mf=0; mf<4; ++mf)
        for (int nf=0; nf<4; ++nf)
          acc[mf][nf] = __builtin_amdgcn_mfma_f32_16x16x32_bf16(a[mf], b[nf], acc[mf][nf], 0,0,0);
    }
  }
  for (int mf=0; mf<4; ++mf)
    for (int nf=0; nf<4; ++nf)
      for (int r=0; r<4; ++r){
        int m = m0 + wm + mf*16 + lg*4 + r;
        int o = n0 + wn + nf*16 + l15;
        float val = acc[mf][nf][r] + pb[o];
        int b_ = m >> 12, s = m & 4095;
        int hh = o / 192, rem = o - hh*192;
        int t = rem >> 6, d = rem & 63;
        size_t bh = (size_t)(b_*NH + hh);
        if (t == 0)      qo [(bh*NS + s)*DK + d] = f2bf(val * QS);
        else if (t == 1) ko [(bh*NS + s)*DK + d] = f2bf(val);
        else             vto[(bh*DK + d)*NS + s] = f2bf(val);
      }
}

// ---- K5: flash attention: 32x32 MFMA, register-P, 16 waves (4 kv-groups x 4 q-subtiles),
//          double-buffered LDS (1 barrier/tile), defer-rescale, XCD-locality swizzle ----
struct SMK { short kv[NKG][2][2][64][72]; };   // [group][buf][K/V][row][col+pad] = 147456 B
struct SMC {                                    // epilogue overlay (138240 B)
  float gOB[3][4][64][33];
  float ml[3][4][2][32];
  float fOB[4][64][33];
};

__global__ __launch_bounds__(1024, 4) void k_attn(const short* __restrict__ q,
                                                  const short* __restrict__ k,
                                                  const short* __restrict__ vt,
                                                  short* __restrict__ ao){
  extern __shared__ char smem[];
  SMK* sk = (SMK*)smem;
  SMC* sc = (SMC*)smem;

  int blk = blockIdx.x;
  // XCD-locality swizzle: XCD = blk%8 (round-robin) -> bh = blk&7 puts all 32
  // q-blocks of one (b,head) on one XCD; its 1MB K/V set becomes L2-resident.
  int bh = blk & 7;
  int q0 = (blk >> 3) << 7;
  const short* Qb = q  + (size_t)bh*NS*DK;
  const short* Kb = k  + (size_t)bh*NS*DK;
  const short* Vb = vt + (size_t)bh*DK*NS;
  int tid = threadIdx.x, lane = tid & 63, wid = tid >> 6;
  int l31 = lane & 31, hi = lane >> 5;
  int g = wid >> 2, wq = wid & 3;
  int gtid = tid & 255;
  int kvbase = g << 10;              // g*1024 kv rows

  // Q regs (B-frag): bq[s2] = Q[q = q0+wq*32+l31][d = s2*16 + hi*8 .. +7]
  short8 bq[4];
  {
    const short* qrow = Qb + (size_t)(q0 + wq*32 + l31)*DK + hi*8;
    #pragma unroll
    for (int s2 = 0; s2 < 4; ++s2) bq[s2] = *(const short8*)(qrow + s2*16);
  }

  f32x16 ot0, ot1;                    // O^T acc: [d-half][reg]; col q = l31
  #pragma unroll
  for (int i = 0; i < 16; ++i){ ot0[i] = 0.f; ot1[i] = 0.f; }
  float mrun = -1e30f, lrun = 0.f;    // per-q (l31), log2 domain

  // staging coords: c = it*256 + gtid -> row r, col (16B chunk)
  short8 kpre[2], vpre[2];
  #pragma unroll
  for (int it = 0; it < 2; ++it){    // tile 0 -> regs
    int c = it*256 + gtid, r = c >> 3, col = (c & 7) << 3;
    kpre[it] = *(const short8*)&Kb[(size_t)(kvbase + r)*DK + col];
    vpre[it] = *(const short8*)&Vb[(size_t)r*NS + kvbase + col];
  }
  #pragma unroll
  for (int it = 0; it < 2; ++it){    // tile 0 -> buf0 (no barrier yet; synced at loop top)
    int c = it*256 + gtid, r = c >> 3, col = (c & 7) << 3;
    *(short8*)&sk->kv[g][0][0][r][col] = kpre[it];
    *(short8*)&sk->kv[g][0][1][r][col] = vpre[it];
  }
  #pragma unroll
  for (int it = 0; it < 2; ++it){    // tile 1 -> regs
    int c = it*256 + gtid, r = c >> 3, col = (c & 7) << 3;
    kpre[it] = *(const short8*)&Kb[(size_t)(kvbase + 64 + r)*DK + col];
    vpre[it] = *(const short8*)&Vb[(size_t)r*NS + kvbase + 64 + col];
  }

  for (int t = 0; t < TPG; ++t){
    __syncthreads();                 // buf[(t+1)&1] free (tile t-1 done) + buf[t&1] ready
    if (t + 1 < TPG){
      int nb = (t + 1) & 1;
      #pragma unroll
      for (int it = 0; it < 2; ++it){
        int c = it*256 + gtid, r = c >> 3, col = (c & 7) << 3;
        *(short8*)&sk->kv[g][nb][0][r][col] = kpre[it];
        *(short8*)&sk->kv[g][nb][1][r][col] = vpre[it];
      }
    }
    if (t + 2 < TPG){
      int kv0 = kvbase + (t + 2)*64;
      #pragma unroll
      for (int it = 0; it < 2; ++it){
        int c = it*256 + gtid, r = c >> 3, col = (c & 7) << 3;
        kpre[it] = *(const short8*)&Kb[(size_t)(kv0 + r)*DK + col];
        vpre[it] = *(const short8*)&Vb[(size_t)r*NS + kv0 + col];
      }
    }
    const short (*Kl)[72] = sk->kv[g][t & 1][0];
    const short (*Vl)[72] = sk->kv[g][t & 1][1];
    // S^T[kv][q] = K x Q
    f32x16 st0, st1;
    #pragma unroll
    for (int i = 0; i < 16; ++i){ st0[i] = 0.f; st1[i] = 0.f; }
    const short* Kr0 = &Kl[l31][hi*8];
    const short* Kr1 = &Kl[32 + l31][hi*8];
    #pragma unroll
    for (int s2 = 0; s2 < 4; ++s2){
      short8 ka0 = *(const short8*)(Kr0 + s2*16);
      short8 ka1 = *(const short8*)(Kr1 + s2*16);
      st0 = __builtin_amdgcn_mfma_f32_32x32x16_bf16(ka0, bq[s2], st0, 0,0,0);
      st1 = __builtin_amdgcn_mfma_f32_32x32x16_bf16(ka1, bq[s2], st1, 0,0,0);
    }
    // online softmax for q = l31 (lane^32 holds the other 32 kv rows)
    float mx = -1e30f;
    #pragma unroll
    for (int i = 0; i < 16; ++i) mx = fmaxf(mx, fmaxf(st0[i], st1[i]));
    mx = fmaxf(mx, __shfl_xor(mx, 32));
    if (!__all(mx - mrun <= 8.f)){   // defer-rescale: P bounded by 2^8, bf16-safe
      float mnew = fmaxf(mrun, mx);
      float corr = ex2(mrun - mnew);
      lrun *= corr;
      #pragma unroll
      for (int i = 0; i < 16; ++i){ ot0[i] *= corr; ot1[i] *= corr; }
      mrun = mnew;
    }
    float p0[16], p1[16]; float ps = 0.f;
    #pragma unroll
    for (int i = 0; i < 16; ++i){
      p0[i] = ex2(st0[i] - mrun); p1[i] = ex2(st1[i] - mrun);
      ps += p0[i] + p1[i];
    }
    ps += __shfl_xor(ps, 32);
    lrun += ps;
    // pack P -> PV B-frags via cvt_pk + permlane32_swap; PV: O^T += V^T x P
    unsigned pk0[8], pk1[8];
    #pragma unroll
    for (int a = 0; a < 4; ++a){
      pk0[a]     = cvtpk(p0[4*a+0], p0[4*a+1]);
      pk1[a]     = cvtpk(p0[4*a+2], p0[4*a+3]);
      pk0[4 + a] = cvtpk(p1[4*a+0], p1[4*a+1]);
      pk1[4 + a] = cvtpk(p1[4*a+2], p1[4*a+3]);
    }
    const short* Vr0 = &Vl[l31][hi*8];
    const short* Vr1 = &Vl[32 + l31][hi*8];
    #pragma unroll
    for (int i2 = 0; i2 < 4; ++i2){
      unsigned w0 = pk0[2*i2], w2 = pk0[2*i2+1]; pl32swap(w0, w2);
      unsigned w1 = pk1[2*i2], w3 = pk1[2*i2+1]; pl32swap(w1, w3);
      U8 cv; cv.u = (uint4v){w0, w1, w2, w3};
      short8 av0 = *(const short8*)(Vr0 + i2*16);
      short8 av1 = *(const short8*)(Vr1 + i2*16);
      ot0 = __builtin_amdgcn_mfma_f32_32x32x16_bf16(av0, cv.s, ot0, 0,0,0);
      ot1 = __builtin_amdgcn_mfma_f32_32x32x16_bf16(av1, cv.s, ot1, 0,0,0);
    }
  }

  // ---- 4-way merge through LDS overlay ----
  __syncthreads();
  if (g > 0){
    #pragma unroll
    for (int r2 = 0; r2 < 16; ++r2){
      int dl = (r2 & 3) + 8*(r2 >> 2) + 4*hi;
      sc->gOB[g-1][wq][dl][l31]      = ot0[r2];
      sc->gOB[g-1][wq][32 + dl][l31] = ot1[r2];
    }
    if (hi == 0){ sc->ml[g-1][wq][0][l31] = mrun; sc->ml[g-1][wq][1][l31] = lrun; }
  }
  __syncthreads();
  if (g == 0){
    float m1 = sc->ml[0][wq][0][l31], l1 = sc->ml[0][wq][1][l31];
    float m2 = sc->ml[1][wq][0][l31], l2 = sc->ml[1][wq][1][l31];
    float m3 = sc->ml[2][wq][0][l31], l3 = sc->ml[2][wq][1][l31];
    float M  = fmaxf(fmaxf(mrun, m1), fmaxf(m2, m3));
    float w0 = ex2(mrun - M), w1 = ex2(m1 - M), w2 = ex2(m2 - M), w3 = ex2(m3 - M);
    float inv = 1.f/(lrun*w0 + l1*w1 + l2*w2 + l3*w3);
    w0 *= inv; w1 *= inv; w2 *= inv; w3 *= inv;
    #pragma unroll
    for (int r2 = 0; r2 < 16; ++r2){
      int dl = (r2 & 3) + 8*(r2 >> 2) + 4*hi;
      sc->fOB[wq][dl][l31] = ot0[r2]*w0 + sc->gOB[0][wq][dl][l31]*w1
                           + sc->gOB[1][wq][dl][l31]*w2 + sc->gOB[2][wq][dl][l31]*w3;
      sc->fOB[wq][32+dl][l31] = ot1[r2]*w0 + sc->gOB[0][wq][32+dl][l31]*w1
                              + sc->gOB[1][wq][32+dl][l31]*w2 + sc->gOB[2][wq][32+dl][l31]*w3;
    }
  }
  __syncthreads();
  // coalesced writeout: 1024 threads, thread -> (q row, 8-d chunk)
  {
    int ql = tid >> 3, dc = (tid & 7) << 3;
    int b_ = bh >> 2, hh = bh & 3;
    float v2[8];
    #pragma unroll
    for (int i = 0; i < 8; ++i) v2[i] = sc->fOB[ql >> 5][dc + i][ql & 31];
    uint4v wa = { cvtpk(v2[0],v2[1]), cvtpk(v2[2],v2[3]),
                  cvtpk(v2[4],v2[5]), cvtpk(v2[6],v2[7]) };
    size_t base = ((size_t)b_*NS + q0 + ql)*NC + hh*DK + dc;
    *(uint4v*)&ao[base] = wa;
  }
}

// ---- K6: out GEMM + bias + residual, BM=64 -> 256 blocks ----
__global__ __launch_bounds__(256) void k_out(const short* __restrict__ aoin,
                                             const short* __restrict__ wb,
                                             const float* __restrict__ ob,
                                             const float* __restrict__ x,
                                             float* __restrict__ out){
  __shared__ short As[64][40];
  __shared__ short Bs[128][40];
  int m0 = blockIdx.x << 6;
  int n0 = blockIdx.y << 7;
  int tid = threadIdx.x;
  int lane = tid & 63, wid = tid >> 6;
  int wm = (wid >> 1) << 5, wn = (wid & 1) << 6;
  int l15 = lane & 15, lg = lane >> 4;
  const f32x4 fz = {0.f,0.f,0.f,0.f};
  f32x4 acc[2][4];
  for (int i=0;i<2;i++) for(int j=0;j<4;j++) acc[i][j] = fz;
  for (int k0 = 0; k0 < NC; k0 += 32){
    __syncthreads();
    {
      int c = tid;
      int r = c >> 2, kk8 = (c & 3) << 3;
      *(short8*)&As[r][kk8] = *(const short8*)&aoin[((size_t)(m0 + r))*NC + k0 + kk8];
    }
    for (int it = 0; it < 2; ++it){
      int c = it*256 + tid;
      int r = c >> 2, kk8 = (c & 3) << 3;
      *(short8*)&Bs[r][kk8] = *(const short8*)&wb[((size_t)(n0 + r))*NC + k0 + kk8];
    }
    __syncthreads();
    short8 a[2], b[4];
    for (int mf=0; mf<2; ++mf) a[mf] = *(const short8*)&As[wm + mf*16 + l15][lg*8];
    for (int nf=0; nf<4; ++nf) b[nf] = *(const short8*)&Bs[wn + nf*16 + l15][lg*8];
    for (int mf=0; mf<2; ++mf)
      for (int nf=0; nf<4; ++nf)
        acc[mf][nf] = __builtin_amdgcn_mfma_f32_16x16x32_bf16(a[mf], b[nf], acc[mf][nf], 0,0,0);
  }
  for (int mf=0; mf<2; ++mf)
    for (int nf=0; nf<4; ++nf)
      for (int r=0; r<4; ++r){
        int m = m0 + wm + mf*16 + lg*4 + r;
        int o = n0 + wn + nf*16 + l15;
        int b_ = m >> 12, s = m & 4095;
        size_t idx = ((size_t)b_*NC + o)*NS + s;
        out[idx] = acc[mf][nf][r] + ob[o] + x[idx];
      }
}

extern "C" void kernel_launch(void* const* d_in, const int* in_sizes, int n_in,
                              void* d_out, int out_size, void* d_ws, size_t ws_size,
                              hipStream_t stream){
  const float* x   = (const float*)d_in[0];
  const float* gnw = (const float*)d_in[1];
  const float* gnb = (const float*)d_in[2];
  const float* pw  = (const float*)d_in[3];
  const float* pb  = (const float*)d_in[4];
  const float* ow  = (const float*)d_in[5];
  const float* ob  = (const float*)d_in[6];
  float* out = (float*)d_out;

  char* ws = (char*)d_ws;
  short* wqkv = (short*)(ws + 512);
  short* wout = wqkv + NQKV*NC;
  short* h    = wout + NC*NC;
  short* qb   = h   + (size_t)NB*NS*NC;
  short* kb   = qb  + (size_t)NB*NH*NS*DK;
  short* vtb  = kb  + (size_t)NB*NH*NS*DK;
  short* ao   = vtb + (size_t)NB*NH*NS*DK;

  k_prep<<<832, 256, 0, stream>>>(x, pw, ow, gnw, gnb, h, wqkv, wout);
  k_qkv<<<dim3(64, 6), 256, 0, stream>>>(h, wqkv, pb, qb, kb, vtb);
  k_attn<<<256, 1024, sizeof(SMK), stream>>>(qb, kb, vtb, ao);
  k_out<<<dim3(128, 2), 256, 0, stream>>>(ao, wout, ob, x, out);
}

// Round 10
// 99.174 us; speedup vs baseline: 2.6281x; 1.0024x over previous
//
#include <hip/hip_runtime.h>
#include <math.h>

#define NB 2
#define NC 256
#define NS 4096
#define NG 32
#define CPG 8
#define NH 4
#define DK 64
#define NQKV 768
#define NKG 4      /* kv groups in k_attn */
#define TPG 16     /* tiles (of 64 kv) per group */
#define QS 0.18033688011112042f   /* 0.125 * log2(e): folds attn scale + exp->exp2 */

typedef __attribute__((ext_vector_type(8))) short short8;
typedef __attribute__((ext_vector_type(4))) float f32x4;
typedef __attribute__((ext_vector_type(16))) float f32x16;
typedef __attribute__((ext_vector_type(4))) unsigned uint4v;

union U8 { uint4v u; short8 s; };

__device__ __forceinline__ short f2bf(float f){
  union { float f; unsigned u; } v; v.f = f;
  unsigned r = v.u + 0x7fffu + ((v.u >> 16) & 1u);
  return (short)(r >> 16);
}
__device__ __forceinline__ float ex2(float x){          // hardware 2^x
  float y; asm("v_exp_f32 %0, %1" : "=v"(y) : "v"(x)); return y;
}
__device__ __forceinline__ unsigned cvtpk(float lo, float hi){ // bf16(lo)|bf16(hi)<<16, RNE
  unsigned u; asm("v_cvt_pk_bf16_f32 %0, %1, %2" : "=v"(u) : "v"(lo), "v"(hi)); return u;
}
// x' (lanes>=32) <- y[lane-32]; y' (lanes<32) <- x[lane+32]
__device__ __forceinline__ void pl32swap(unsigned &x, unsigned &y){
  asm("v_permlane32_swap_b32 %0, %1" : "+v"(x), "+v"(y));
}

// ---- K1: fused group-norm (stats + apply + transpose-write of h) and weight cvt ----
__global__ __launch_bounds__(256) void k_prep(const float* __restrict__ x,
                                              const float* __restrict__ pw,
                                              const float* __restrict__ ow,
                                              const float* __restrict__ gw,
                                              const float* __restrict__ gb,
                                              short* __restrict__ h,
                                              short* __restrict__ pwb,
                                              short* __restrict__ owb){
  int bk = blockIdx.x;
  int tid = threadIdx.x;
  if (bk < 64){
    int b = bk >> 5, g = bk & 31;
    const float* base = x + (size_t)bk*(CPG*NS);
    const f32x4* b4 = (const f32x4*)base;
    float s = 0.f, ss = 0.f;
    for (int i = tid; i < (CPG*NS)/4; i += 256){
      f32x4 v = b4[i];
      s  += (v[0]+v[1])+(v[2]+v[3]);
      ss += (v[0]*v[0]+v[1]*v[1])+(v[2]*v[2]+v[3]*v[3]);
    }
    for (int o = 32; o > 0; o >>= 1){ s += __shfl_down(s,o); ss += __shfl_down(ss,o); }
    __shared__ float red[8];
    __shared__ float mrs[2];
    int w = tid >> 6;
    if ((tid & 63) == 0){ red[w] = s; red[4+w] = ss; }
    __syncthreads();
    if (tid == 0){
      float S  = red[0]+red[1]+red[2]+red[3];
      float SS = red[4]+red[5]+red[6]+red[7];
      const float inv = 1.f/(float)(CPG*NS);
      float m = S*inv; float var = SS*inv - m*m;
      mrs[0] = m; mrs[1] = rsqrtf(var + 1e-5f);
    }
    __syncthreads();
    float mu = mrs[0], rs = mrs[1];
    float wv[8], bv[8];
    #pragma unroll
    for (int c = 0; c < 8; ++c){
      wv[c] = gw[g*8 + c] * rs;
      bv[c] = gb[g*8 + c] - mu * wv[c];
    }
    short* hb = h + (size_t)b*NS*NC + g*8;
    for (int i = tid; i < NS; i += 256){
      unsigned u[4];
      #pragma unroll
      for (int c2 = 0; c2 < 4; ++c2){
        float v0 = base[(size_t)(2*c2  )*NS + i]*wv[2*c2  ] + bv[2*c2  ];
        float v1 = base[(size_t)(2*c2+1)*NS + i]*wv[2*c2+1] + bv[2*c2+1];
        u[c2] = cvtpk(v0, v1);
      }
      *(uint4v*)&hb[(size_t)i*NC] = (uint4v){u[0],u[1],u[2],u[3]};
    }
  } else {
    int i = (bk - 64)*256 + tid;
    if (i < NQKV*NC) pwb[i] = f2bf(pw[i]);
    if (i < NC*NC)   owb[i] = f2bf(ow[i]);
  }
}

// ---- K4: QKV GEMM, BM=64 BK=64 -> 768 blocks; scatter epilogue; q gets QS folded ----
__global__ __launch_bounds__(256) void k_qkv(const short* __restrict__ h,
                                             const short* __restrict__ wb,
                                             const float* __restrict__ pb,
                                             short* __restrict__ qo,
                                             short* __restrict__ ko,
                                             short* __restrict__ vto){
  __shared__ short As[64][72];
  __shared__ short Bs[128][72];
  int m0 = blockIdx.x << 6;
  int n0 = blockIdx.y << 7;
  int tid = threadIdx.x;
  int lane = tid & 63, wid = tid >> 6;
  int wm = (wid >> 1) << 5, wn = (wid & 1) << 6;
  int l15 = lane & 15, lg = lane >> 4;
  const f32x4 fz = {0.f,0.f,0.f,0.f};
  f32x4 acc[2][4];
  for (int i=0;i<2;i++) for(int j=0;j<4;j++) acc[i][j] = fz;
  for (int k0 = 0; k0 < NC; k0 += 64){
    __syncthreads();
    for (int it = 0; it < 2; ++it){
      int c = it*256 + tid;
      int r = c >> 3, ch = (c & 7) << 3;
      *(short8*)&As[r][ch] = *(const short8*)&h[((size_t)(m0 + r))*NC + k0 + ch];
    }
    for (int it = 0; it < 4; ++it){
      int c = it*256 + tid;
      int r = c >> 3, ch = (c & 7) << 3;
      *(short8*)&Bs[r][ch] = *(const short8*)&wb[((size_t)(n0 + r))*NC + k0 + ch];
    }
    __syncthreads();
    #pragma unroll
    for (int kk = 0; kk < 2; ++kk){
      short8 a[2], b[4];
      for (int mf=0; mf<2; ++mf) a[mf] = *(const short8*)&As[wm + mf*16 + l15][kk*32 + lg*8];
      for (int nf=0; nf<4; ++nf) b[nf] = *(const short8*)&Bs[wn + nf*16 + l15][kk*32 + lg*8];
      for (int mf=0; mf<2; ++mf)
        for (int nf=0; nf<4; ++nf)
          acc[mf][nf] = __builtin_amdgcn_mfma_f32_16x16x32_bf16(a[mf], b[nf], acc[mf][nf], 0,0,0);
    }
  }
  for (int mf=0; mf<2; ++mf)
    for (int nf=0; nf<4; ++nf)
      for (int r=0; r<4; ++r){
        int m = m0 + wm + mf*16 + lg*4 + r;
        int o = n0 + wn + nf*16 + l15;
        float val = acc[mf][nf][r] + pb[o];
        int b_ = m >> 12, s = m & 4095;
        int hh = o / 192, rem = o - hh*192;
        int t = rem >> 6, d = rem & 63;
        size_t bh = (size_t)(b_*NH + hh);
        if (t == 0)      qo [(bh*NS + s)*DK + d] = f2bf(val * QS);
        else if (t == 1) ko [(bh*NS + s)*DK + d] = f2bf(val);
        else             vto[(bh*DK + d)*NS + s] = f2bf(val);
      }
}

// ---- K5: flash attention: 32x32 MFMA, register-P, 16 waves, dbuf LDS (1 barrier/tile),
//          defer-rescale, XCD swizzle; QK hoisted ahead of staging (chain-shortening) ----
struct SMK { short kv[NKG][2][2][64][72]; };   // 147456 B
struct SMC {                                    // epilogue overlay
  float gOB[3][4][64][33];
  float ml[3][4][2][32];
  float fOB[4][64][33];
};

__global__ __launch_bounds__(1024, 4) void k_attn(const short* __restrict__ q,
                                                  const short* __restrict__ k,
                                                  const short* __restrict__ vt,
                                                  short* __restrict__ ao){
  extern __shared__ char smem[];
  SMK* sk = (SMK*)smem;
  SMC* sc = (SMC*)smem;

  int blk = blockIdx.x;
  // XCD-locality swizzle: bh = blk&7 -> one (b,head)'s 1MB K/V per XCD (L2-resident)
  int bh = blk & 7;
  int q0 = (blk >> 3) << 7;
  const short* Qb = q  + (size_t)bh*NS*DK;
  const short* Kb = k  + (size_t)bh*NS*DK;
  const short* Vb = vt + (size_t)bh*DK*NS;
  int tid = threadIdx.x, lane = tid & 63, wid = tid >> 6;
  int l31 = lane & 31, hi = lane >> 5;
  int g = wid >> 2, wq = wid & 3;
  int gtid = tid & 255;
  int kvbase = g << 10;

  short8 bq[4];
  {
    const short* qrow = Qb + (size_t)(q0 + wq*32 + l31)*DK + hi*8;
    #pragma unroll
    for (int s2 = 0; s2 < 4; ++s2) bq[s2] = *(const short8*)(qrow + s2*16);
  }

  f32x16 ot0, ot1;
  #pragma unroll
  for (int i = 0; i < 16; ++i){ ot0[i] = 0.f; ot1[i] = 0.f; }
  float mrun = -1e30f, lrun = 0.f;

  short8 kpre[2], vpre[2];
  #pragma unroll
  for (int it = 0; it < 2; ++it){    // tile 0 -> regs
    int c = it*256 + gtid, r = c >> 3, col = (c & 7) << 3;
    kpre[it] = *(const short8*)&Kb[(size_t)(kvbase + r)*DK + col];
    vpre[it] = *(const short8*)&Vb[(size_t)r*NS + kvbase + col];
  }
  #pragma unroll
  for (int it = 0; it < 2; ++it){    // tile 0 -> buf0
    int c = it*256 + gtid, r = c >> 3, col = (c & 7) << 3;
    *(short8*)&sk->kv[g][0][0][r][col] = kpre[it];
    *(short8*)&sk->kv[g][0][1][r][col] = vpre[it];
  }
  #pragma unroll
  for (int it = 0; it < 2; ++it){    // tile 1 -> regs
    int c = it*256 + gtid, r = c >> 3, col = (c & 7) << 3;
    kpre[it] = *(const short8*)&Kb[(size_t)(kvbase + 64 + r)*DK + col];
    vpre[it] = *(const short8*)&Vb[(size_t)r*NS + kvbase + 64 + col];
  }

  for (int t = 0; t < TPG; ++t){
    __syncthreads();                 // buf[t&1] ready; buf[(t+1)&1] free
    const short (*Kl)[72] = sk->kv[g][t & 1][0];
    const short (*Vl)[72] = sk->kv[g][t & 1][1];
    // ---- QK FIRST: ds_reads + MFMAs issue before staging (compiler can't prove
    //      buf[t&1] reads don't alias buf[(t+1)&1] writes, so order it manually).
    //      DS pipe is per-wave in-order: K reads beat the t+1 writes into the queue.
    f32x16 st0, st1;
    #pragma unroll
    for (int i = 0; i < 16; ++i){ st0[i] = 0.f; st1[i] = 0.f; }
    const short* Kr0 = &Kl[l31][hi*8];
    const short* Kr1 = &Kl[32 + l31][hi*8];
    #pragma unroll
    for (int s2 = 0; s2 < 4; ++s2){
      short8 ka0 = *(const short8*)(Kr0 + s2*16);
      short8 ka1 = *(const short8*)(Kr1 + s2*16);
      st0 = __builtin_amdgcn_mfma_f32_32x32x16_bf16(ka0, bq[s2], st0, 0,0,0);
      st1 = __builtin_amdgcn_mfma_f32_32x32x16_bf16(ka1, bq[s2], st1, 0,0,0);
    }
    // ---- staging: LDS writes for t+1, global prefetch t+2 (overlap MFMA latency)
    if (t + 1 < TPG){
      int nb = (t + 1) & 1;
      #pragma unroll
      for (int it = 0; it < 2; ++it){
        int c = it*256 + gtid, r = c >> 3, col = (c & 7) << 3;
        *(short8*)&sk->kv[g][nb][0][r][col] = kpre[it];
        *(short8*)&sk->kv[g][nb][1][r][col] = vpre[it];
      }
    }
    if (t + 2 < TPG){
      int kv0 = kvbase + (t + 2)*64;
      #pragma unroll
      for (int it = 0; it < 2; ++it){
        int c = it*256 + gtid, r = c >> 3, col = (c & 7) << 3;
        kpre[it] = *(const short8*)&Kb[(size_t)(kv0 + r)*DK + col];
        vpre[it] = *(const short8*)&Vb[(size_t)r*NS + kv0 + col];
      }
    }
    // ---- softmax (VALU; overlaps DS/VMEM pipes working through staging)
    float mx = -1e30f;
    #pragma unroll
    for (int i = 0; i < 16; ++i) mx = fmaxf(mx, fmaxf(st0[i], st1[i]));
    mx = fmaxf(mx, __shfl_xor(mx, 32));
    if (!__all(mx - mrun <= 8.f)){
      float mnew = fmaxf(mrun, mx);
      float corr = ex2(mrun - mnew);
      lrun *= corr;
      #pragma unroll
      for (int i = 0; i < 16; ++i){ ot0[i] *= corr; ot1[i] *= corr; }
      mrun = mnew;
    }
    float p0[16], p1[16]; float ps = 0.f;
    #pragma unroll
    for (int i = 0; i < 16; ++i){
      p0[i] = ex2(st0[i] - mrun); p1[i] = ex2(st1[i] - mrun);
      ps += p0[i] + p1[i];
    }
    ps += __shfl_xor(ps, 32);
    lrun += ps;
    unsigned pk0[8], pk1[8];
    #pragma unroll
    for (int a = 0; a < 4; ++a){
      pk0[a]     = cvtpk(p0[4*a+0], p0[4*a+1]);
      pk1[a]     = cvtpk(p0[4*a+2], p0[4*a+3]);
      pk0[4 + a] = cvtpk(p1[4*a+0], p1[4*a+1]);
      pk1[4 + a] = cvtpk(p1[4*a+2], p1[4*a+3]);
    }
    const short* Vr0 = &Vl[l31][hi*8];
    const short* Vr1 = &Vl[32 + l31][hi*8];
    #pragma unroll
    for (int i2 = 0; i2 < 4; ++i2){
      unsigned w0 = pk0[2*i2], w2 = pk0[2*i2+1]; pl32swap(w0, w2);
      unsigned w1 = pk1[2*i2], w3 = pk1[2*i2+1]; pl32swap(w1, w3);
      U8 cv; cv.u = (uint4v){w0, w1, w2, w3};
      short8 av0 = *(const short8*)(Vr0 + i2*16);
      short8 av1 = *(const short8*)(Vr1 + i2*16);
      ot0 = __builtin_amdgcn_mfma_f32_32x32x16_bf16(av0, cv.s, ot0, 0,0,0);
      ot1 = __builtin_amdgcn_mfma_f32_32x32x16_bf16(av1, cv.s, ot1, 0,0,0);
    }
  }

  // ---- 4-way merge through LDS overlay ----
  __syncthreads();
  if (g > 0){
    #pragma unroll
    for (int r2 = 0; r2 < 16; ++r2){
      int dl = (r2 & 3) + 8*(r2 >> 2) + 4*hi;
      sc->gOB[g-1][wq][dl][l31]      = ot0[r2];
      sc->gOB[g-1][wq][32 + dl][l31] = ot1[r2];
    }
    if (hi == 0){ sc->ml[g-1][wq][0][l31] = mrun; sc->ml[g-1][wq][1][l31] = lrun; }
  }
  __syncthreads();
  if (g == 0){
    float m1 = sc->ml[0][wq][0][l31], l1 = sc->ml[0][wq][1][l31];
    float m2 = sc->ml[1][wq][0][l31], l2 = sc->ml[1][wq][1][l31];
    float m3 = sc->ml[2][wq][0][l31], l3 = sc->ml[2][wq][1][l31];
    float M  = fmaxf(fmaxf(mrun, m1), fmaxf(m2, m3));
    float w0 = ex2(mrun - M), w1 = ex2(m1 - M), w2 = ex2(m2 - M), w3 = ex2(m3 - M);
    float inv = 1.f/(lrun*w0 + l1*w1 + l2*w2 + l3*w3);
    w0 *= inv; w1 *= inv; w2 *= inv; w3 *= inv;
    #pragma unroll
    for (int r2 = 0; r2 < 16; ++r2){
      int dl = (r2 & 3) + 8*(r2 >> 2) + 4*hi;
      sc->fOB[wq][dl][l31] = ot0[r2]*w0 + sc->gOB[0][wq][dl][l31]*w1
                           + sc->gOB[1][wq][dl][l31]*w2 + sc->gOB[2][wq][dl][l31]*w3;
      sc->fOB[wq][32+dl][l31] = ot1[r2]*w0 + sc->gOB[0][wq][32+dl][l31]*w1
                              + sc->gOB[1][wq][32+dl][l31]*w2 + sc->gOB[2][wq][32+dl][l31]*w3;
    }
  }
  __syncthreads();
  {
    int ql = tid >> 3, dc = (tid & 7) << 3;
    int b_ = bh >> 2, hh = bh & 3;
    float v2[8];
    #pragma unroll
    for (int i = 0; i < 8; ++i) v2[i] = sc->fOB[ql >> 5][dc + i][ql & 31];
    uint4v wa = { cvtpk(v2[0],v2[1]), cvtpk(v2[2],v2[3]),
                  cvtpk(v2[4],v2[5]), cvtpk(v2[6],v2[7]) };
    size_t base = ((size_t)b_*NS + q0 + ql)*NC + hh*DK + dc;
    *(uint4v*)&ao[base] = wa;
  }
}

// ---- K6: out GEMM + bias + residual, BM=64 BN=64 -> 512 blocks ----
__global__ __launch_bounds__(256) void k_out(const short* __restrict__ aoin,
                                             const short* __restrict__ wb,
                                             const float* __restrict__ ob,
                                             const float* __restrict__ x,
                                             float* __restrict__ out){
  __shared__ short As[64][40];
  __shared__ short Bs[64][40];
  int m0 = blockIdx.x << 6;
  int n0 = blockIdx.y << 6;
  int tid = threadIdx.x;
  int lane = tid & 63, wid = tid >> 6;
  int wm = (wid >> 1) << 5, wn = (wid & 1) << 5;
  int l15 = lane & 15, lg = lane >> 4;
  const f32x4 fz = {0.f,0.f,0.f,0.f};
  f32x4 acc[2][2];
  for (int i=0;i<2;i++) for(int j=0;j<2;j++) acc[i][j] = fz;
  for (int k0 = 0; k0 < NC; k0 += 32){
    __syncthreads();
    {
      int c = tid;
      int r = c >> 2, kk8 = (c & 3) << 3;
      *(short8*)&As[r][kk8] = *(const short8*)&aoin[((size_t)(m0 + r))*NC + k0 + kk8];
      *(short8*)&Bs[r][kk8] = *(const short8*)&wb  [((size_t)(n0 + r))*NC + k0 + kk8];
    }
    __syncthreads();
    short8 a[2], b[2];
    for (int mf=0; mf<2; ++mf) a[mf] = *(const short8*)&As[wm + mf*16 + l15][lg*8];
    for (int nf=0; nf<2; ++nf) b[nf] = *(const short8*)&Bs[wn + nf*16 + l15][lg*8];
    for (int mf=0; mf<2; ++mf)
      for (int nf=0; nf<2; ++nf)
        acc[mf][nf] = __builtin_amdgcn_mfma_f32_16x16x32_bf16(a[mf], b[nf], acc[mf][nf], 0,0,0);
  }
  for (int mf=0; mf<2; ++mf)
    for (int nf=0; nf<2; ++nf)
      for (int r=0; r<4; ++r){
        int m = m0 + wm + mf*16 + lg*4 + r;
        int o = n0 + wn + nf*16 + l15;
        int b_ = m >> 12, s = m & 4095;
        size_t idx = ((size_t)b_*NC + o)*NS + s;
        out[idx] = acc[mf][nf][r] + ob[o] + x[idx];
      }
}

extern "C" void kernel_launch(void* const* d_in, const int* in_sizes, int n_in,
                              void* d_out, int out_size, void* d_ws, size_t ws_size,
                              hipStream_t stream){
  const float* x   = (const float*)d_in[0];
  const float* gnw = (const float*)d_in[1];
  const float* gnb = (const float*)d_in[2];
  const float* pw  = (const float*)d_in[3];
  const float* pb  = (const float*)d_in[4];
  const float* ow  = (const float*)d_in[5];
  const float* ob  = (const float*)d_in[6];
  float* out = (float*)d_out;

  char* ws = (char*)d_ws;
  short* wqkv = (short*)(ws + 512);
  short* wout = wqkv + NQKV*NC;
  short* h    = wout + NC*NC;
  short* qb   = h   + (size_t)NB*NS*NC;
  short* kb   = qb  + (size_t)NB*NH*NS*DK;
  short* vtb  = kb  + (size_t)NB*NH*NS*DK;
  short* ao   = vtb + (size_t)NB*NH*NS*DK;

  k_prep<<<832, 256, 0, stream>>>(x, pw, ow, gnw, gnb, h, wqkv, wout);
  k_qkv<<<dim3(128, 6), 256, 0, stream>>>(h, wqkv, pb, qb, kb, vtb);
  k_attn<<<256, 1024, sizeof(SMK), stream>>>(qb, kb, vtb, ao);
  k_out<<<dim3(128, 4), 256, 0, stream>>>(ao, wout, ob, x, out);
}